// Round 6
// baseline (250.185 us; speedup 1.0000x reference)
//
#include <hip/hip_runtime.h>
#include <math.h>
#include <stdint.h>

#define BB 8
#define SS 2048
#define EE 1024
#define DKK 64

typedef _Float16 half8 __attribute__((ext_vector_type(8)));
typedef float floatx4 __attribute__((ext_vector_type(4)));

__device__ __forceinline__ void split8(float4 a, float4 b, half8& hi, half8& lo) {
  float va[8] = {a.x, a.y, a.z, a.w, b.x, b.y, b.z, b.w};
#pragma unroll
  for (int j = 0; j < 8; ++j) {
    _Float16 h = (_Float16)va[j];
    hi[j] = h;
    lo[j] = (_Float16)(va[j] - (float)h);
  }
}

// ---------------------------------------------------------------------------
// W pre-split: fp32 [3][64][1024] -> fp16 hi/lo. 96 blocks x 256 thr x 8 elems.
// ---------------------------------------------------------------------------
__global__ __launch_bounds__(256) void wsplit_kernel(
    const float* __restrict__ w_q, const float* __restrict__ w_k,
    const float* __restrict__ w_v, _Float16* __restrict__ Whi,
    _Float16* __restrict__ Wlo) {
  const int idx = ((int)blockIdx.x * 256 + (int)threadIdx.x) * 8;
  const int v = idx >> 16;  // 65536 floats per variant
  const int off = idx & 65535;
  const float* W = v == 0 ? w_q : (v == 1 ? w_k : w_v);
  float4 a = *(const float4*)(W + off);
  float4 b = *(const float4*)(W + off + 4);
  half8 hi, lo;
  split8(a, b, hi, lo);
  *(half8*)(Whi + idx) = hi;
  *(half8*)(Wlo + idx) = lo;
}

// ---------------------------------------------------------------------------
// Barrier-free MFMA projection, split-fp16 (3-term): P = Xh*Wh + Xh*Wl + Xl*Wh.
// No LDS. blockIdx.y = 0:Q, 1:K, 2:V(transposed out). 256 thr, 4 waves,
// wave w: rows blockIdx.x*64 + w*16 .. +15, all 64 cols.
// A-frags: X direct from global (fp32, split in-reg); B-frags: Whi/Wlo direct
// (L1/L2-hot, 8 KB working set per K-chunk shared by all waves).
// ---------------------------------------------------------------------------
__global__ __launch_bounds__(256) void proj_kernel(
    const float* __restrict__ q_in, const float* __restrict__ k_in,
    const float* __restrict__ v_in,
    const _Float16* __restrict__ Whi, const _Float16* __restrict__ Wlo,
    const float* __restrict__ b_q, const float* __restrict__ b_k,
    const float* __restrict__ b_v,
    _Float16* __restrict__ Qh, _Float16* __restrict__ Kh,
    _Float16* __restrict__ VhT) {
  const int which = blockIdx.y;
  const float* X = which == 0 ? q_in : (which == 1 ? k_in : v_in);
  const float* bias = which == 0 ? b_q : (which == 1 ? b_k : b_v);
  const _Float16* wh = Whi + which * 65536;
  const _Float16* wl = Wlo + which * 65536;

  const int t = threadIdx.x;
  const int l = t & 63;
  const int li = l & 15, g = l >> 4;
  const int w = t >> 6;
  const int row0 = (int)blockIdx.x * 64;
  const float* xrow = X + (size_t)(row0 + w * 16 + li) * EE + g * 8;

  floatx4 acc[4];
#pragma unroll
  for (int c = 0; c < 4; ++c) acc[c] = (floatx4){0.f, 0.f, 0.f, 0.f};

  // software pipeline: X chunk k+1 loads issued while chunk k computes
  float4 xa = ((const float4*)xrow)[0];
  float4 xb = ((const float4*)xrow)[1];
  for (int e0 = 0; e0 < EE; e0 += 32) {
    float4 na, nb;
    if (e0 + 32 < EE) {
      na = ((const float4*)(xrow + e0 + 32))[0];
      nb = ((const float4*)(xrow + e0 + 32))[1];
    }
    half8 axh, axl;
    split8(xa, xb, axh, axl);
    const int wo = e0 + g * 8;
#pragma unroll
    for (int c = 0; c < 4; ++c) {
      const int wrow = (c * 16 + li) * EE + wo;
      const half8 bh = *(const half8*)(wh + wrow);
      const half8 bl = *(const half8*)(wl + wrow);
      acc[c] = __builtin_amdgcn_mfma_f32_16x16x32_f16(axh, bh, acc[c], 0, 0, 0);
      acc[c] = __builtin_amdgcn_mfma_f32_16x16x32_f16(axh, bl, acc[c], 0, 0, 0);
      acc[c] = __builtin_amdgcn_mfma_f32_16x16x32_f16(axl, bh, acc[c], 0, 0, 0);
    }
    xa = na;
    xb = nb;
  }

  float bvv[4];
#pragma unroll
  for (int c = 0; c < 4; ++c) bvv[c] = bias[c * 16 + li];

  if (which < 2) {
    _Float16* P = (which == 0) ? Qh : Kh;
#pragma unroll
    for (int c = 0; c < 4; ++c)
#pragma unroll
      for (int r = 0; r < 4; ++r)
        P[(size_t)(row0 + w * 16 + g * 4 + r) * DKK + c * 16 + li] =
            (_Float16)(acc[c][r] + bvv[c]);
  } else {
    const int bb = row0 >> 11;
    const int s0 = row0 & (SS - 1);
#pragma unroll
    for (int c = 0; c < 4; ++c)
#pragma unroll
      for (int r = 0; r < 4; ++r)
        VhT[((size_t)bb * DKK + c * 16 + li) * SS + s0 + w * 16 + g * 4 + r] =
            (_Float16)(acc[c][r] + bvv[c]);
  }
}

// ---------------------------------------------------------------------------
// Flash kernel (unchanged from round 5): single-pass swapped-QK attention.
// ---------------------------------------------------------------------------
__global__ __launch_bounds__(512, 4) void flash_kernel(
    const _Float16* __restrict__ Qh, const _Float16* __restrict__ Kh,
    const _Float16* __restrict__ VhT, const int* __restrict__ mask,
    float* __restrict__ outsc, uint32_t* __restrict__ mbits_g,
    float* __restrict__ mstats) {
  __shared__ __align__(16) char Vlds[16384];  // [64 d][128 k] f16, swz src
  __shared__ uint32_t mwords[32][66];         // mask bits, padded
  __shared__ float Obuf[32][68];              // combine buffer, padded
  __shared__ float mlbuf[8][16][2];           // per-wave (m, l)
  __shared__ float lstat[32][2];              // per-q (m*, 1/l*)

  const int t = threadIdx.x;
  const int b = (int)blockIdx.x & 7;
  const int q0 = ((int)blockIdx.x >> 3) * 32;
  const int l = t & 63;
  const int li = l & 15, g = l >> 4;
  const int w = t >> 6;
  const int qh = w & 1, ws = w >> 1;
  const float SCALE = 0.125f;

  // ---- pack mask: thread t packs words [t*4, t*4+4) (32 ints each) ----
  {
    const int* mp = mask + ((size_t)b * SS + q0) * SS;
    uint32_t wbuf[4];
#pragma unroll
    for (int u = 0; u < 4; ++u) {
      const int word = t * 4 + u;
      const int4* src = (const int4*)(mp + word * 32);
      uint32_t bits = 0;
#pragma unroll
      for (int c = 0; c < 8; ++c) {
        int4 m4 = src[c];
        bits |= (uint32_t)(m4.x != 0) << (c * 4 + 0);
        bits |= (uint32_t)(m4.y != 0) << (c * 4 + 1);
        bits |= (uint32_t)(m4.z != 0) << (c * 4 + 2);
        bits |= (uint32_t)(m4.w != 0) << (c * 4 + 3);
      }
      wbuf[u] = bits;
      mwords[word >> 6][word & 63] = bits;
    }
    *(uint4*)(mbits_g + ((size_t)(b * SS + q0)) * 64 + t * 4) =
        *(const uint4*)wbuf;
  }

  half8 aq[2];
  {
    const _Float16* qp = Qh + ((size_t)b * SS + q0 + qh * 16 + li) * DKK;
    aq[0] = *(const half8*)(qp + g * 8);
    aq[1] = *(const half8*)(qp + 32 + g * 8);
  }

  float m_c = -3.0e38f, l_c = 0.f;
  floatx4 O[4];
#pragma unroll
  for (int d = 0; d < 4; ++d) O[d] = (floatx4){0.f, 0.f, 0.f, 0.f};

  half8 vv[2];
#pragma unroll
  for (int p = 0; p < 2; ++p) {
    const int slot = t + p * 512;
    const int vd = slot >> 4, vc = slot & 15;
    vv[p] = *(const half8*)(VhT + ((size_t)b * DKK + vd) * SS +
                            ((vc ^ (vd & 7)) * 8));
  }

  const _Float16* kbase = Kh + (size_t)b * SS * DKK;

  for (int kt = 0; kt < 16; ++kt) {
    __syncthreads();
#pragma unroll
    for (int p = 0; p < 2; ++p)
      *(half8*)(Vlds + (t + p * 512) * 16) = vv[p];
    __syncthreads();
    if (kt + 1 < 16) {
#pragma unroll
      for (int p = 0; p < 2; ++p) {
        const int slot = t + p * 512;
        const int vd = slot >> 4, vc = slot & 15;
        vv[p] = *(const half8*)(VhT + ((size_t)b * DKK + vd) * SS +
                                (kt + 1) * 128 + ((vc ^ (vd & 7)) * 8));
      }
    }

    half8 ka[2][2];
#pragma unroll
    for (int cb = 0; cb < 2; ++cb) {
      const int krow = ws * 32 + cb * 16 + li;
      const _Float16* kp = kbase + (size_t)(kt * 128 + krow) * DKK;
      ka[cb][0] = *(const half8*)(kp + g * 8);
      ka[cb][1] = *(const half8*)(kp + 32 + g * 8);
    }
    floatx4 sc[2];
#pragma unroll
    for (int cb = 0; cb < 2; ++cb) {
      floatx4 acc = {0.f, 0.f, 0.f, 0.f};
      acc = __builtin_amdgcn_mfma_f32_16x16x32_f16(ka[cb][0], aq[0], acc, 0, 0, 0);
      acc = __builtin_amdgcn_mfma_f32_16x16x32_f16(ka[cb][1], aq[1], acc, 0, 0, 0);
      sc[cb] = acc;
    }

    const uint32_t mw = mwords[qh * 16 + li][kt * 4 + ws];
    float p[2][4];
    float tmax = -3.0e38f;
#pragma unroll
    for (int cb = 0; cb < 2; ++cb)
#pragma unroll
      for (int r = 0; r < 4; ++r) {
        const float s =
            ((mw >> (cb * 16 + g * 4 + r)) & 1u) ? sc[cb][r] * SCALE : -1.0e9f;
        p[cb][r] = s;
        tmax = fmaxf(tmax, s);
      }
    tmax = fmaxf(tmax, __shfl_xor(tmax, 16));
    tmax = fmaxf(tmax, __shfl_xor(tmax, 32));
    const float m_new = fmaxf(m_c, tmax);
    const float alpha = __expf(m_c - m_new);
    m_c = m_new;
    float lsum = 0.f;
#pragma unroll
    for (int cb = 0; cb < 2; ++cb)
#pragma unroll
      for (int r = 0; r < 4; ++r) {
        p[cb][r] = __expf(p[cb][r] - m_new);
        lsum += p[cb][r];
      }
    l_c = l_c * alpha + lsum;

    half8 pB;
#pragma unroll
    for (int j = 0; j < 4; ++j) {
      pB[j] = (_Float16)p[0][j];
      pB[4 + j] = (_Float16)p[1][j];
    }

#pragma unroll
    for (int dblk = 0; dblk < 4; ++dblk) {
      const int d = dblk * 16 + li;
      const int rowb = d * 256;
      const int c1 = ws * 4 + (g >> 1);
      const int c2 = c1 + 2;
      const int sub = (g & 1) * 8;
      uint2 a1 = *(const uint2*)(Vlds + rowb + ((c1 ^ (li & 7)) * 16) + sub);
      uint2 a2 = *(const uint2*)(Vlds + rowb + ((c2 ^ (li & 7)) * 16) + sub);
      half8 av;
      *(uint2*)&av = a1;
      *((uint2*)&av + 1) = a2;
      O[dblk] = O[dblk] * alpha;
      O[dblk] = __builtin_amdgcn_mfma_f32_16x16x32_f16(av, pB, O[dblk], 0, 0, 0);
    }
  }

  l_c += __shfl_xor(l_c, 16);
  l_c += __shfl_xor(l_c, 32);
  if (g == 0) {
    mlbuf[w][li][0] = m_c;
    mlbuf[w][li][1] = l_c;
  }
  __syncthreads();
  float mstar = -3.0e38f;
#pragma unroll
  for (int p2 = 0; p2 < 4; ++p2)
    mstar = fmaxf(mstar, mlbuf[p2 * 2 + qh][li][0]);
  float lstar = 0.f;
#pragma unroll
  for (int p2 = 0; p2 < 4; ++p2)
    lstar += mlbuf[p2 * 2 + qh][li][1] * __expf(mlbuf[p2 * 2 + qh][li][0] - mstar);
  const float fown = __expf(m_c - mstar);
  if (g == 0 && ws == 0) {
    lstat[qh * 16 + li][0] = mstar;
    lstat[qh * 16 + li][1] = 1.f / lstar;
  }
#pragma unroll
  for (int dblk = 0; dblk < 4; ++dblk) O[dblk] = O[dblk] * fown;

  for (int ph = 0; ph < 4; ++ph) {
    if (ws == ph) {
      const int qq = qh * 16 + li;
#pragma unroll
      for (int dblk = 0; dblk < 4; ++dblk)
#pragma unroll
        for (int r = 0; r < 4; ++r) {
          const int d = dblk * 16 + g * 4 + r;
          if (ph == 0)
            Obuf[qq][d] = O[dblk][r];
          else
            Obuf[qq][d] += O[dblk][r];
        }
    }
    __syncthreads();
  }

  {
    const int qq = t >> 4;
    const int d0 = (t & 15) * 4;
    const float rl = lstat[qq][1];
    float4 o;
    o.x = Obuf[qq][d0 + 0] * rl;
    o.y = Obuf[qq][d0 + 1] * rl;
    o.z = Obuf[qq][d0 + 2] * rl;
    o.w = Obuf[qq][d0 + 3] * rl;
    *(float4*)(outsc + ((size_t)(b * SS + q0 + qq)) * DKK + d0) = o;
  }
  if (t < 32) {
    mstats[((size_t)(b * SS + q0 + t)) * 2 + 0] = lstat[t][0];
    mstats[((size_t)(b * SS + q0 + t)) * 2 + 1] = lstat[t][1];
  }
}

// ---------------------------------------------------------------------------
// Weights kernel (unchanged): streaming GEMM + exp, no LDS, no barriers.
// ---------------------------------------------------------------------------
__global__ __launch_bounds__(512) void weights_kernel(
    const _Float16* __restrict__ Qh, const _Float16* __restrict__ Kh,
    const uint32_t* __restrict__ mbits_g, const float* __restrict__ mstats,
    float* __restrict__ wts) {
  const int t = threadIdx.x;
  const int b = (int)blockIdx.x & 7;
  const int q0 = ((int)blockIdx.x >> 3) * 32;
  const int l = t & 63;
  const int li = l & 15, g = l >> 4;
  const int w = t >> 6;
  const int qh = w & 1, cq = w >> 1;
  const float SCALE = 0.125f;

  half8 aq[2];
  {
    const _Float16* qp = Qh + ((size_t)b * SS + q0 + qh * 16 + li) * DKK;
    aq[0] = *(const half8*)(qp + g * 8);
    aq[1] = *(const half8*)(qp + 32 + g * 8);
  }
  float mr[4], rl[4];
#pragma unroll
  for (int r = 0; r < 4; ++r) {
    const size_t q = (size_t)b * SS + q0 + qh * 16 + g * 4 + r;
    mr[r] = mstats[q * 2 + 0];
    rl[r] = mstats[q * 2 + 1];
  }
  const _Float16* kbase = Kh + (size_t)b * SS * DKK;

  for (int kt = 0; kt < 16; ++kt) {
    uint32_t mw[4];
#pragma unroll
    for (int r = 0; r < 4; ++r)
      mw[r] = mbits_g[((size_t)(b * SS + q0 + qh * 16 + g * 4 + r)) * 64 +
                      kt * 4 + cq];
    half8 kb[2][2];
#pragma unroll
    for (int cb = 0; cb < 2; ++cb) {
      const int krow = cq * 32 + cb * 16 + li;
      const _Float16* kp = kbase + (size_t)(kt * 128 + krow) * DKK;
      kb[cb][0] = *(const half8*)(kp + g * 8);
      kb[cb][1] = *(const half8*)(kp + 32 + g * 8);
    }
#pragma unroll
    for (int cb = 0; cb < 2; ++cb) {
      floatx4 acc = {0.f, 0.f, 0.f, 0.f};
      acc = __builtin_amdgcn_mfma_f32_16x16x32_f16(aq[0], kb[cb][0], acc, 0, 0, 0);
      acc = __builtin_amdgcn_mfma_f32_16x16x32_f16(aq[1], kb[cb][1], acc, 0, 0, 0);
#pragma unroll
      for (int r = 0; r < 4; ++r) {
        const float wv = ((mw[r] >> (cb * 16 + li)) & 1u)
                             ? __expf(acc[r] * SCALE - mr[r]) * rl[r]
                             : 0.f;
        wts[((size_t)(b * SS + q0 + qh * 16 + g * 4 + r)) * SS + kt * 128 +
            cq * 32 + cb * 16 + li] = wv;
      }
    }
  }
}

extern "C" void kernel_launch(void* const* d_in, const int* in_sizes, int n_in,
                              void* d_out, int out_size, void* d_ws, size_t ws_size,
                              hipStream_t stream) {
  (void)in_sizes; (void)n_in; (void)out_size; (void)ws_size;
  const float* k_in = (const float*)d_in[0];
  const float* q_in = (const float*)d_in[1];
  const float* v_in = (const float*)d_in[2];
  const int* mask = (const int*)d_in[3];
  const float* w_q = (const float*)d_in[4];
  const float* b_q = (const float*)d_in[5];
  const float* w_k = (const float*)d_in[6];
  const float* b_k = (const float*)d_in[7];
  const float* w_v = (const float*)d_in[8];
  const float* b_v = (const float*)d_in[9];

  float* out_scores = (float*)d_out;                        // [B,S,DK] f32
  float* out_weights = out_scores + (size_t)BB * SS * DKK;  // [B,S,S]  f32

  char* wsp = (char*)d_ws;
  const size_t nBSD = (size_t)BB * SS * DKK;
  _Float16* Qh = (_Float16*)wsp;                      // 2 MB
  _Float16* Kh = (_Float16*)(wsp + nBSD * 2);         // 2 MB
  _Float16* VhT = (_Float16*)(wsp + nBSD * 4);        // 2 MB
  uint32_t* mbits_g = (uint32_t*)(wsp + nBSD * 6);    // 4 MB
  float* mstats = (float*)(wsp + nBSD * 6 + (size_t)BB * SS * 64 * 4);  // 128 KB
  _Float16* Whi = (_Float16*)(wsp + nBSD * 6 + (size_t)BB * SS * 64 * 4 +
                              (size_t)BB * SS * 2 * 4);
  _Float16* Wlo = Whi + 3 * 65536;

  wsplit_kernel<<<96, 256, 0, stream>>>(w_q, w_k, w_v, Whi, Wlo);
  proj_kernel<<<dim3(256, 3), 256, 0, stream>>>(q_in, k_in, v_in, Whi, Wlo,
                                                b_q, b_k, b_v, Qh, Kh, VhT);
  flash_kernel<<<512, 512, 0, stream>>>(Qh, Kh, VhT, mask, out_scores,
                                        mbits_g, mstats);
  weights_kernel<<<512, 512, 0, stream>>>(Qh, Kh, mbits_g, mstats, out_weights);
}

// Round 7
// 208.607 us; speedup vs baseline: 1.1993x; 1.1993x over previous
//
#include <hip/hip_runtime.h>
#include <math.h>
#include <stdint.h>

#define BB 8
#define SS 2048
#define EE 1024
#define DKK 64

typedef _Float16 half8 __attribute__((ext_vector_type(8)));
typedef float floatx4 __attribute__((ext_vector_type(4)));

__device__ __forceinline__ void split8(float4 a, float4 b, half8& hi, half8& lo) {
  float va[8] = {a.x, a.y, a.z, a.w, b.x, b.y, b.z, b.w};
#pragma unroll
  for (int j = 0; j < 8; ++j) {
    _Float16 h = (_Float16)va[j];
    hi[j] = h;
    lo[j] = (_Float16)(va[j] - (float)h);
  }
}

// ---------------------------------------------------------------------------
// W pre-split + fragment-permute: Whi/Wlo laid out as
//   [variant][kchunk(e0/32)][c(0..3)][lane(0..63)][8 halfs]
// so proj's B-fragment load is base + lane*16B (fully coalesced).
// Slot s: l = s&63, c = (s>>6)&3, ch = (s>>8)&31, v = s>>13.
// Lane (g=l>>4, li=l&15) holds W[v][col=c*16+li][k=ch*32+g*8 .. +7].
// ---------------------------------------------------------------------------
__global__ __launch_bounds__(256) void wsplit_kernel(
    const float* __restrict__ w_q, const float* __restrict__ w_k,
    const float* __restrict__ w_v, _Float16* __restrict__ Whi,
    _Float16* __restrict__ Wlo) {
  const int s = (int)blockIdx.x * 256 + (int)threadIdx.x;  // 0..24575
  const int l = s & 63;
  const int c = (s >> 6) & 3;
  const int ch = (s >> 8) & 31;
  const int v = s >> 13;
  const int li = l & 15, g = l >> 4;
  const float* W = v == 0 ? w_q : (v == 1 ? w_k : w_v);
  const float* src = W + (size_t)(c * 16 + li) * EE + ch * 32 + g * 8;
  float4 a = *(const float4*)src;
  float4 b = *(const float4*)(src + 4);
  half8 hi, lo;
  split8(a, b, hi, lo);
  *(half8*)(Whi + (size_t)s * 8) = hi;
  *(half8*)(Wlo + (size_t)s * 8) = lo;
}

// ---------------------------------------------------------------------------
// Barrier-free MFMA projection, split-fp16 (3-term): P = Xh*Wh + Xh*Wl + Xl*Wh.
// No LDS, no barriers. B-fragments now COALESCED (fragment-order W).
// blockIdx.y = 0:Q, 1:K, 2:V(transposed out). 256 thr / 4 waves,
// wave w: rows blockIdx.x*64 + w*16 .. +15, all 64 cols.
// ---------------------------------------------------------------------------
__global__ __launch_bounds__(256) void proj_kernel(
    const float* __restrict__ q_in, const float* __restrict__ k_in,
    const float* __restrict__ v_in,
    const _Float16* __restrict__ Whi, const _Float16* __restrict__ Wlo,
    const float* __restrict__ b_q, const float* __restrict__ b_k,
    const float* __restrict__ b_v,
    _Float16* __restrict__ Qh, _Float16* __restrict__ Kh,
    _Float16* __restrict__ VhT) {
  const int which = blockIdx.y;
  const float* X = which == 0 ? q_in : (which == 1 ? k_in : v_in);
  const float* bias = which == 0 ? b_q : (which == 1 ? b_k : b_v);
  const _Float16* wh = Whi + which * 65536;
  const _Float16* wl = Wlo + which * 65536;

  const int t = threadIdx.x;
  const int l = t & 63;
  const int li = l & 15, g = l >> 4;
  const int w = t >> 6;
  const int row0 = (int)blockIdx.x * 64;
  const float* xrow = X + (size_t)(row0 + w * 16 + li) * EE + g * 8;

  floatx4 acc[4];
#pragma unroll
  for (int c = 0; c < 4; ++c) acc[c] = (floatx4){0.f, 0.f, 0.f, 0.f};

  // software pipeline: X chunk k+1 loads issued while chunk k computes
  float4 xa = ((const float4*)xrow)[0];
  float4 xb = ((const float4*)xrow)[1];
  for (int e0 = 0; e0 < EE; e0 += 32) {
    float4 na, nb;
    if (e0 + 32 < EE) {
      na = ((const float4*)(xrow + e0 + 32))[0];
      nb = ((const float4*)(xrow + e0 + 32))[1];
    }
    half8 axh, axl;
    split8(xa, xb, axh, axl);
    const int ch4 = (e0 >> 5) * 4;  // kchunk * 4
#pragma unroll
    for (int c = 0; c < 4; ++c) {
      const int fo = ((ch4 + c) * 64 + l) * 8;  // fragment offset (coalesced)
      const half8 bh = *(const half8*)(wh + fo);
      const half8 bl = *(const half8*)(wl + fo);
      acc[c] = __builtin_amdgcn_mfma_f32_16x16x32_f16(axh, bh, acc[c], 0, 0, 0);
      acc[c] = __builtin_amdgcn_mfma_f32_16x16x32_f16(axh, bl, acc[c], 0, 0, 0);
      acc[c] = __builtin_amdgcn_mfma_f32_16x16x32_f16(axl, bh, acc[c], 0, 0, 0);
    }
    xa = na;
    xb = nb;
  }

  float bvv[4];
#pragma unroll
  for (int c = 0; c < 4; ++c) bvv[c] = bias[c * 16 + li];

  if (which < 2) {
    _Float16* P = (which == 0) ? Qh : Kh;
#pragma unroll
    for (int c = 0; c < 4; ++c)
#pragma unroll
      for (int r = 0; r < 4; ++r)
        P[(size_t)(row0 + w * 16 + g * 4 + r) * DKK + c * 16 + li] =
            (_Float16)(acc[c][r] + bvv[c]);
  } else {
    const int bb = row0 >> 11;
    const int s0 = row0 & (SS - 1);
#pragma unroll
    for (int c = 0; c < 4; ++c)
#pragma unroll
      for (int r = 0; r < 4; ++r)
        VhT[((size_t)bb * DKK + c * 16 + li) * SS + s0 + w * 16 + g * 4 + r] =
            (_Float16)(acc[c][r] + bvv[c]);
  }
}

// ---------------------------------------------------------------------------
// Flash kernel (unchanged): single-pass swapped-QK attention.
// ---------------------------------------------------------------------------
__global__ __launch_bounds__(512, 4) void flash_kernel(
    const _Float16* __restrict__ Qh, const _Float16* __restrict__ Kh,
    const _Float16* __restrict__ VhT, const int* __restrict__ mask,
    float* __restrict__ outsc, uint32_t* __restrict__ mbits_g,
    float* __restrict__ mstats) {
  __shared__ __align__(16) char Vlds[16384];  // [64 d][128 k] f16, swz src
  __shared__ uint32_t mwords[32][66];         // mask bits, padded
  __shared__ float Obuf[32][68];              // combine buffer, padded
  __shared__ float mlbuf[8][16][2];           // per-wave (m, l)
  __shared__ float lstat[32][2];              // per-q (m*, 1/l*)

  const int t = threadIdx.x;
  const int b = (int)blockIdx.x & 7;
  const int q0 = ((int)blockIdx.x >> 3) * 32;
  const int l = t & 63;
  const int li = l & 15, g = l >> 4;
  const int w = t >> 6;
  const int qh = w & 1, ws = w >> 1;
  const float SCALE = 0.125f;

  // ---- pack mask: thread t packs words [t*4, t*4+4) (32 ints each) ----
  {
    const int* mp = mask + ((size_t)b * SS + q0) * SS;
    uint32_t wbuf[4];
#pragma unroll
    for (int u = 0; u < 4; ++u) {
      const int word = t * 4 + u;
      const int4* src = (const int4*)(mp + word * 32);
      uint32_t bits = 0;
#pragma unroll
      for (int c = 0; c < 8; ++c) {
        int4 m4 = src[c];
        bits |= (uint32_t)(m4.x != 0) << (c * 4 + 0);
        bits |= (uint32_t)(m4.y != 0) << (c * 4 + 1);
        bits |= (uint32_t)(m4.z != 0) << (c * 4 + 2);
        bits |= (uint32_t)(m4.w != 0) << (c * 4 + 3);
      }
      wbuf[u] = bits;
      mwords[word >> 6][word & 63] = bits;
    }
    *(uint4*)(mbits_g + ((size_t)(b * SS + q0)) * 64 + t * 4) =
        *(const uint4*)wbuf;
  }

  half8 aq[2];
  {
    const _Float16* qp = Qh + ((size_t)b * SS + q0 + qh * 16 + li) * DKK;
    aq[0] = *(const half8*)(qp + g * 8);
    aq[1] = *(const half8*)(qp + 32 + g * 8);
  }

  float m_c = -3.0e38f, l_c = 0.f;
  floatx4 O[4];
#pragma unroll
  for (int d = 0; d < 4; ++d) O[d] = (floatx4){0.f, 0.f, 0.f, 0.f};

  half8 vv[2];
#pragma unroll
  for (int p = 0; p < 2; ++p) {
    const int slot = t + p * 512;
    const int vd = slot >> 4, vc = slot & 15;
    vv[p] = *(const half8*)(VhT + ((size_t)b * DKK + vd) * SS +
                            ((vc ^ (vd & 7)) * 8));
  }

  const _Float16* kbase = Kh + (size_t)b * SS * DKK;

  for (int kt = 0; kt < 16; ++kt) {
    __syncthreads();
#pragma unroll
    for (int p = 0; p < 2; ++p)
      *(half8*)(Vlds + (t + p * 512) * 16) = vv[p];
    __syncthreads();
    if (kt + 1 < 16) {
#pragma unroll
      for (int p = 0; p < 2; ++p) {
        const int slot = t + p * 512;
        const int vd = slot >> 4, vc = slot & 15;
        vv[p] = *(const half8*)(VhT + ((size_t)b * DKK + vd) * SS +
                                (kt + 1) * 128 + ((vc ^ (vd & 7)) * 8));
      }
    }

    half8 ka[2][2];
#pragma unroll
    for (int cb = 0; cb < 2; ++cb) {
      const int krow = ws * 32 + cb * 16 + li;
      const _Float16* kp = kbase + (size_t)(kt * 128 + krow) * DKK;
      ka[cb][0] = *(const half8*)(kp + g * 8);
      ka[cb][1] = *(const half8*)(kp + 32 + g * 8);
    }
    floatx4 sc[2];
#pragma unroll
    for (int cb = 0; cb < 2; ++cb) {
      floatx4 acc = {0.f, 0.f, 0.f, 0.f};
      acc = __builtin_amdgcn_mfma_f32_16x16x32_f16(ka[cb][0], aq[0], acc, 0, 0, 0);
      acc = __builtin_amdgcn_mfma_f32_16x16x32_f16(ka[cb][1], aq[1], acc, 0, 0, 0);
      sc[cb] = acc;
    }

    const uint32_t mw = mwords[qh * 16 + li][kt * 4 + ws];
    float p[2][4];
    float tmax = -3.0e38f;
#pragma unroll
    for (int cb = 0; cb < 2; ++cb)
#pragma unroll
      for (int r = 0; r < 4; ++r) {
        const float s =
            ((mw >> (cb * 16 + g * 4 + r)) & 1u) ? sc[cb][r] * SCALE : -1.0e9f;
        p[cb][r] = s;
        tmax = fmaxf(tmax, s);
      }
    tmax = fmaxf(tmax, __shfl_xor(tmax, 16));
    tmax = fmaxf(tmax, __shfl_xor(tmax, 32));
    const float m_new = fmaxf(m_c, tmax);
    const float alpha = __expf(m_c - m_new);
    m_c = m_new;
    float lsum = 0.f;
#pragma unroll
    for (int cb = 0; cb < 2; ++cb)
#pragma unroll
      for (int r = 0; r < 4; ++r) {
        p[cb][r] = __expf(p[cb][r] - m_new);
        lsum += p[cb][r];
      }
    l_c = l_c * alpha + lsum;

    half8 pB;
#pragma unroll
    for (int j = 0; j < 4; ++j) {
      pB[j] = (_Float16)p[0][j];
      pB[4 + j] = (_Float16)p[1][j];
    }

#pragma unroll
    for (int dblk = 0; dblk < 4; ++dblk) {
      const int d = dblk * 16 + li;
      const int rowb = d * 256;
      const int c1 = ws * 4 + (g >> 1);
      const int c2 = c1 + 2;
      const int sub = (g & 1) * 8;
      uint2 a1 = *(const uint2*)(Vlds + rowb + ((c1 ^ (li & 7)) * 16) + sub);
      uint2 a2 = *(const uint2*)(Vlds + rowb + ((c2 ^ (li & 7)) * 16) + sub);
      half8 av;
      *(uint2*)&av = a1;
      *((uint2*)&av + 1) = a2;
      O[dblk] = O[dblk] * alpha;
      O[dblk] = __builtin_amdgcn_mfma_f32_16x16x32_f16(av, pB, O[dblk], 0, 0, 0);
    }
  }

  l_c += __shfl_xor(l_c, 16);
  l_c += __shfl_xor(l_c, 32);
  if (g == 0) {
    mlbuf[w][li][0] = m_c;
    mlbuf[w][li][1] = l_c;
  }
  __syncthreads();
  float mstar = -3.0e38f;
#pragma unroll
  for (int p2 = 0; p2 < 4; ++p2)
    mstar = fmaxf(mstar, mlbuf[p2 * 2 + qh][li][0]);
  float lstar = 0.f;
#pragma unroll
  for (int p2 = 0; p2 < 4; ++p2)
    lstar += mlbuf[p2 * 2 + qh][li][1] * __expf(mlbuf[p2 * 2 + qh][li][0] - mstar);
  const float fown = __expf(m_c - mstar);
  if (g == 0 && ws == 0) {
    lstat[qh * 16 + li][0] = mstar;
    lstat[qh * 16 + li][1] = 1.f / lstar;
  }
#pragma unroll
  for (int dblk = 0; dblk < 4; ++dblk) O[dblk] = O[dblk] * fown;

  for (int ph = 0; ph < 4; ++ph) {
    if (ws == ph) {
      const int qq = qh * 16 + li;
#pragma unroll
      for (int dblk = 0; dblk < 4; ++dblk)
#pragma unroll
        for (int r = 0; r < 4; ++r) {
          const int d = dblk * 16 + g * 4 + r;
          if (ph == 0)
            Obuf[qq][d] = O[dblk][r];
          else
            Obuf[qq][d] += O[dblk][r];
        }
    }
    __syncthreads();
  }

  {
    const int qq = t >> 4;
    const int d0 = (t & 15) * 4;
    const float rl = lstat[qq][1];
    float4 o;
    o.x = Obuf[qq][d0 + 0] * rl;
    o.y = Obuf[qq][d0 + 1] * rl;
    o.z = Obuf[qq][d0 + 2] * rl;
    o.w = Obuf[qq][d0 + 3] * rl;
    *(float4*)(outsc + ((size_t)(b * SS + q0 + qq)) * DKK + d0) = o;
  }
  if (t < 32) {
    mstats[((size_t)(b * SS + q0 + t)) * 2 + 0] = lstat[t][0];
    mstats[((size_t)(b * SS + q0 + t)) * 2 + 1] = lstat[t][1];
  }
}

// ---------------------------------------------------------------------------
// Weights kernel (unchanged): streaming GEMM + exp, no LDS, no barriers.
// ---------------------------------------------------------------------------
__global__ __launch_bounds__(512) void weights_kernel(
    const _Float16* __restrict__ Qh, const _Float16* __restrict__ Kh,
    const uint32_t* __restrict__ mbits_g, const float* __restrict__ mstats,
    float* __restrict__ wts) {
  const int t = threadIdx.x;
  const int b = (int)blockIdx.x & 7;
  const int q0 = ((int)blockIdx.x >> 3) * 32;
  const int l = t & 63;
  const int li = l & 15, g = l >> 4;
  const int w = t >> 6;
  const int qh = w & 1, cq = w >> 1;
  const float SCALE = 0.125f;

  half8 aq[2];
  {
    const _Float16* qp = Qh + ((size_t)b * SS + q0 + qh * 16 + li) * DKK;
    aq[0] = *(const half8*)(qp + g * 8);
    aq[1] = *(const half8*)(qp + 32 + g * 8);
  }
  float mr[4], rl[4];
#pragma unroll
  for (int r = 0; r < 4; ++r) {
    const size_t q = (size_t)b * SS + q0 + qh * 16 + g * 4 + r;
    mr[r] = mstats[q * 2 + 0];
    rl[r] = mstats[q * 2 + 1];
  }
  const _Float16* kbase = Kh + (size_t)b * SS * DKK;

  for (int kt = 0; kt < 16; ++kt) {
    uint32_t mw[4];
#pragma unroll
    for (int r = 0; r < 4; ++r)
      mw[r] = mbits_g[((size_t)(b * SS + q0 + qh * 16 + g * 4 + r)) * 64 +
                      kt * 4 + cq];
    half8 kb[2][2];
#pragma unroll
    for (int cb = 0; cb < 2; ++cb) {
      const int krow = cq * 32 + cb * 16 + li;
      const _Float16* kp = kbase + (size_t)(kt * 128 + krow) * DKK;
      kb[cb][0] = *(const half8*)(kp + g * 8);
      kb[cb][1] = *(const half8*)(kp + 32 + g * 8);
    }
#pragma unroll
    for (int cb = 0; cb < 2; ++cb) {
      floatx4 acc = {0.f, 0.f, 0.f, 0.f};
      acc = __builtin_amdgcn_mfma_f32_16x16x32_f16(aq[0], kb[cb][0], acc, 0, 0, 0);
      acc = __builtin_amdgcn_mfma_f32_16x16x32_f16(aq[1], kb[cb][1], acc, 0, 0, 0);
#pragma unroll
      for (int r = 0; r < 4; ++r) {
        const float wv = ((mw[r] >> (cb * 16 + li)) & 1u)
                             ? __expf(acc[r] * SCALE - mr[r]) * rl[r]
                             : 0.f;
        wts[((size_t)(b * SS + q0 + qh * 16 + g * 4 + r)) * SS + kt * 128 +
            cq * 32 + cb * 16 + li] = wv;
      }
    }
  }
}

extern "C" void kernel_launch(void* const* d_in, const int* in_sizes, int n_in,
                              void* d_out, int out_size, void* d_ws, size_t ws_size,
                              hipStream_t stream) {
  (void)in_sizes; (void)n_in; (void)out_size; (void)ws_size;
  const float* k_in = (const float*)d_in[0];
  const float* q_in = (const float*)d_in[1];
  const float* v_in = (const float*)d_in[2];
  const int* mask = (const int*)d_in[3];
  const float* w_q = (const float*)d_in[4];
  const float* b_q = (const float*)d_in[5];
  const float* w_k = (const float*)d_in[6];
  const float* b_k = (const float*)d_in[7];
  const float* w_v = (const float*)d_in[8];
  const float* b_v = (const float*)d_in[9];

  float* out_scores = (float*)d_out;                        // [B,S,DK] f32
  float* out_weights = out_scores + (size_t)BB * SS * DKK;  // [B,S,S]  f32

  char* wsp = (char*)d_ws;
  const size_t nBSD = (size_t)BB * SS * DKK;
  _Float16* Qh = (_Float16*)wsp;                      // 2 MB
  _Float16* Kh = (_Float16*)(wsp + nBSD * 2);         // 2 MB
  _Float16* VhT = (_Float16*)(wsp + nBSD * 4);        // 2 MB
  uint32_t* mbits_g = (uint32_t*)(wsp + nBSD * 6);    // 4 MB
  float* mstats = (float*)(wsp + nBSD * 6 + (size_t)BB * SS * 64 * 4);  // 128 KB
  _Float16* Whi = (_Float16*)(wsp + nBSD * 6 + (size_t)BB * SS * 64 * 4 +
                              (size_t)BB * SS * 2 * 4);
  _Float16* Wlo = Whi + 3 * 65536;

  wsplit_kernel<<<96, 256, 0, stream>>>(w_q, w_k, w_v, Whi, Wlo);
  proj_kernel<<<dim3(256, 3), 256, 0, stream>>>(q_in, k_in, v_in, Whi, Wlo,
                                                b_q, b_k, b_v, Qh, Kh, VhT);
  flash_kernel<<<512, 512, 0, stream>>>(Qh, Kh, VhT, mask, out_scores,
                                        mbits_g, mstats);
  weights_kernel<<<512, 512, 0, stream>>>(Qh, Kh, mbits_g, mstats, out_weights);
}

// Round 8
// 207.968 us; speedup vs baseline: 1.2030x; 1.0031x over previous
//
#include <hip/hip_runtime.h>
#include <math.h>
#include <stdint.h>

#define BB 8
#define SS 2048
#define EE 1024
#define DKK 64

typedef _Float16 half8 __attribute__((ext_vector_type(8)));
typedef float floatx4 __attribute__((ext_vector_type(4)));

__device__ __forceinline__ void split8(float4 a, float4 b, half8& hi, half8& lo) {
  float va[8] = {a.x, a.y, a.z, a.w, b.x, b.y, b.z, b.w};
#pragma unroll
  for (int j = 0; j < 8; ++j) {
    _Float16 h = (_Float16)va[j];
    hi[j] = h;
    lo[j] = (_Float16)(va[j] - (float)h);
  }
}

// ---------------------------------------------------------------------------
// W pre-split + fragment-permute (unchanged):
//   Whi/Wlo[variant][kchunk][c][lane][8] -> B-frag load = base + lane*16B.
// ---------------------------------------------------------------------------
__global__ __launch_bounds__(256) void wsplit_kernel(
    const float* __restrict__ w_q, const float* __restrict__ w_k,
    const float* __restrict__ w_v, _Float16* __restrict__ Whi,
    _Float16* __restrict__ Wlo) {
  const int s = (int)blockIdx.x * 256 + (int)threadIdx.x;  // 0..24575
  const int l = s & 63;
  const int c = (s >> 6) & 3;
  const int ch = (s >> 8) & 31;
  const int v = s >> 13;
  const int li = l & 15, g = l >> 4;
  const float* W = v == 0 ? w_q : (v == 1 ? w_k : w_v);
  const float* src = W + (size_t)(c * 16 + li) * EE + ch * 32 + g * 8;
  float4 a = *(const float4*)src;
  float4 b = *(const float4*)(src + 4);
  half8 hi, lo;
  split8(a, b, hi, lo);
  *(half8*)(Whi + (size_t)s * 8) = hi;
  *(half8*)(Wlo + (size_t)s * 8) = lo;
}

// ---------------------------------------------------------------------------
// MFMA projection, split-fp16 (3-term), K-split across waves.
// 512 thr / 8 waves; wave (rg = w&3, ks = w>>2): rows blockIdx.x*64+rg*16..+15,
// all 64 cols, K-half ks*512..+511. 2-deep register prefetch on X.
// Combine: ks=1 -> LDS partials, barrier, ks=0 adds + epilogue.
// ---------------------------------------------------------------------------
__global__ __launch_bounds__(512) void proj_kernel(
    const float* __restrict__ q_in, const float* __restrict__ k_in,
    const float* __restrict__ v_in,
    const _Float16* __restrict__ Whi, const _Float16* __restrict__ Wlo,
    const float* __restrict__ b_q, const float* __restrict__ b_k,
    const float* __restrict__ b_v,
    _Float16* __restrict__ Qh, _Float16* __restrict__ Kh,
    _Float16* __restrict__ VhT) {
  const int which = blockIdx.y;
  const float* X = which == 0 ? q_in : (which == 1 ? k_in : v_in);
  const float* bias = which == 0 ? b_q : (which == 1 ? b_k : b_v);
  const _Float16* wh = Whi + which * 65536;
  const _Float16* wl = Wlo + which * 65536;

  __shared__ float partial[4][64][16];  // [rg][lane][c*4+r] = 16 KB

  const int t = threadIdx.x;
  const int l = t & 63;
  const int li = l & 15, g = l >> 4;
  const int w = t >> 6;
  const int rg = w & 3, ks = w >> 2;
  const int row0 = (int)blockIdx.x * 64;
  const float* xrow = X + (size_t)(row0 + rg * 16 + li) * EE + ks * 512 + g * 8;
  const int ch0 = ks * 16;  // first kchunk of this half

  floatx4 acc[4];
#pragma unroll
  for (int c = 0; c < 4; ++c) acc[c] = (floatx4){0.f, 0.f, 0.f, 0.f};

  // 2-deep software pipeline over 16 chunks of 32 floats
  float4 xa0 = ((const float4*)(xrow + 0 * 32))[0];
  float4 xb0 = ((const float4*)(xrow + 0 * 32))[1];
  float4 xa1 = ((const float4*)(xrow + 1 * 32))[0];
  float4 xb1 = ((const float4*)(xrow + 1 * 32))[1];

#pragma unroll 2
  for (int e = 0; e < 16; e += 2) {
    // ---- stage A: compute chunk e, prefetch chunk e+2 ----
    {
      float4 na, nb;
      if (e + 2 < 16) {
        na = ((const float4*)(xrow + (e + 2) * 32))[0];
        nb = ((const float4*)(xrow + (e + 2) * 32))[1];
      }
      half8 axh, axl;
      split8(xa0, xb0, axh, axl);
      const int base = (ch0 + e) * 4;
#pragma unroll
      for (int c = 0; c < 4; ++c) {
        const int fo = ((base + c) * 64 + l) * 8;
        const half8 bh = *(const half8*)(wh + fo);
        const half8 bl = *(const half8*)(wl + fo);
        acc[c] = __builtin_amdgcn_mfma_f32_16x16x32_f16(axh, bh, acc[c], 0, 0, 0);
        acc[c] = __builtin_amdgcn_mfma_f32_16x16x32_f16(axh, bl, acc[c], 0, 0, 0);
        acc[c] = __builtin_amdgcn_mfma_f32_16x16x32_f16(axl, bh, acc[c], 0, 0, 0);
      }
      xa0 = na;
      xb0 = nb;
    }
    // ---- stage B: compute chunk e+1, prefetch chunk e+3 ----
    {
      float4 na, nb;
      if (e + 3 < 16) {
        na = ((const float4*)(xrow + (e + 3) * 32))[0];
        nb = ((const float4*)(xrow + (e + 3) * 32))[1];
      }
      half8 axh, axl;
      split8(xa1, xb1, axh, axl);
      const int base = (ch0 + e + 1) * 4;
#pragma unroll
      for (int c = 0; c < 4; ++c) {
        const int fo = ((base + c) * 64 + l) * 8;
        const half8 bh = *(const half8*)(wh + fo);
        const half8 bl = *(const half8*)(wl + fo);
        acc[c] = __builtin_amdgcn_mfma_f32_16x16x32_f16(axh, bh, acc[c], 0, 0, 0);
        acc[c] = __builtin_amdgcn_mfma_f32_16x16x32_f16(axh, bl, acc[c], 0, 0, 0);
        acc[c] = __builtin_amdgcn_mfma_f32_16x16x32_f16(axl, bh, acc[c], 0, 0, 0);
      }
      xa1 = na;
      xb1 = nb;
    }
  }

  // ---- combine the two K-halves ----
  if (ks == 1) {
#pragma unroll
    for (int c = 0; c < 4; ++c)
#pragma unroll
      for (int r = 0; r < 4; ++r) partial[rg][l][c * 4 + r] = acc[c][r];
  }
  __syncthreads();
  if (ks == 0) {
#pragma unroll
    for (int c = 0; c < 4; ++c)
#pragma unroll
      for (int r = 0; r < 4; ++r) acc[c][r] += partial[rg][l][c * 4 + r];

    float bvv[4];
#pragma unroll
    for (int c = 0; c < 4; ++c) bvv[c] = bias[c * 16 + li];

    if (which < 2) {
      _Float16* P = (which == 0) ? Qh : Kh;
#pragma unroll
      for (int c = 0; c < 4; ++c)
#pragma unroll
        for (int r = 0; r < 4; ++r)
          P[(size_t)(row0 + rg * 16 + g * 4 + r) * DKK + c * 16 + li] =
              (_Float16)(acc[c][r] + bvv[c]);
    } else {
      const int bb = row0 >> 11;
      const int s0 = row0 & (SS - 1);
#pragma unroll
      for (int c = 0; c < 4; ++c)
#pragma unroll
        for (int r = 0; r < 4; ++r)
          VhT[((size_t)bb * DKK + c * 16 + li) * SS + s0 + rg * 16 + g * 4 + r] =
              (_Float16)(acc[c][r] + bvv[c]);
    }
  }
}

// ---------------------------------------------------------------------------
// Flash kernel (unchanged): single-pass swapped-QK attention.
// ---------------------------------------------------------------------------
__global__ __launch_bounds__(512, 4) void flash_kernel(
    const _Float16* __restrict__ Qh, const _Float16* __restrict__ Kh,
    const _Float16* __restrict__ VhT, const int* __restrict__ mask,
    float* __restrict__ outsc, uint32_t* __restrict__ mbits_g,
    float* __restrict__ mstats) {
  __shared__ __align__(16) char Vlds[16384];  // [64 d][128 k] f16, swz src
  __shared__ uint32_t mwords[32][66];         // mask bits, padded
  __shared__ float Obuf[32][68];              // combine buffer, padded
  __shared__ float mlbuf[8][16][2];           // per-wave (m, l)
  __shared__ float lstat[32][2];              // per-q (m*, 1/l*)

  const int t = threadIdx.x;
  const int b = (int)blockIdx.x & 7;
  const int q0 = ((int)blockIdx.x >> 3) * 32;
  const int l = t & 63;
  const int li = l & 15, g = l >> 4;
  const int w = t >> 6;
  const int qh = w & 1, ws = w >> 1;
  const float SCALE = 0.125f;

  // ---- pack mask: thread t packs words [t*4, t*4+4) (32 ints each) ----
  {
    const int* mp = mask + ((size_t)b * SS + q0) * SS;
    uint32_t wbuf[4];
#pragma unroll
    for (int u = 0; u < 4; ++u) {
      const int word = t * 4 + u;
      const int4* src = (const int4*)(mp + word * 32);
      uint32_t bits = 0;
#pragma unroll
      for (int c = 0; c < 8; ++c) {
        int4 m4 = src[c];
        bits |= (uint32_t)(m4.x != 0) << (c * 4 + 0);
        bits |= (uint32_t)(m4.y != 0) << (c * 4 + 1);
        bits |= (uint32_t)(m4.z != 0) << (c * 4 + 2);
        bits |= (uint32_t)(m4.w != 0) << (c * 4 + 3);
      }
      wbuf[u] = bits;
      mwords[word >> 6][word & 63] = bits;
    }
    *(uint4*)(mbits_g + ((size_t)(b * SS + q0)) * 64 + t * 4) =
        *(const uint4*)wbuf;
  }

  half8 aq[2];
  {
    const _Float16* qp = Qh + ((size_t)b * SS + q0 + qh * 16 + li) * DKK;
    aq[0] = *(const half8*)(qp + g * 8);
    aq[1] = *(const half8*)(qp + 32 + g * 8);
  }

  float m_c = -3.0e38f, l_c = 0.f;
  floatx4 O[4];
#pragma unroll
  for (int d = 0; d < 4; ++d) O[d] = (floatx4){0.f, 0.f, 0.f, 0.f};

  half8 vv[2];
#pragma unroll
  for (int p = 0; p < 2; ++p) {
    const int slot = t + p * 512;
    const int vd = slot >> 4, vc = slot & 15;
    vv[p] = *(const half8*)(VhT + ((size_t)b * DKK + vd) * SS +
                            ((vc ^ (vd & 7)) * 8));
  }

  const _Float16* kbase = Kh + (size_t)b * SS * DKK;

  for (int kt = 0; kt < 16; ++kt) {
    __syncthreads();
#pragma unroll
    for (int p = 0; p < 2; ++p)
      *(half8*)(Vlds + (t + p * 512) * 16) = vv[p];
    __syncthreads();
    if (kt + 1 < 16) {
#pragma unroll
      for (int p = 0; p < 2; ++p) {
        const int slot = t + p * 512;
        const int vd = slot >> 4, vc = slot & 15;
        vv[p] = *(const half8*)(VhT + ((size_t)b * DKK + vd) * SS +
                                (kt + 1) * 128 + ((vc ^ (vd & 7)) * 8));
      }
    }

    half8 ka[2][2];
#pragma unroll
    for (int cb = 0; cb < 2; ++cb) {
      const int krow = ws * 32 + cb * 16 + li;
      const _Float16* kp = kbase + (size_t)(kt * 128 + krow) * DKK;
      ka[cb][0] = *(const half8*)(kp + g * 8);
      ka[cb][1] = *(const half8*)(kp + 32 + g * 8);
    }
    floatx4 sc[2];
#pragma unroll
    for (int cb = 0; cb < 2; ++cb) {
      floatx4 acc = {0.f, 0.f, 0.f, 0.f};
      acc = __builtin_amdgcn_mfma_f32_16x16x32_f16(ka[cb][0], aq[0], acc, 0, 0, 0);
      acc = __builtin_amdgcn_mfma_f32_16x16x32_f16(ka[cb][1], aq[1], acc, 0, 0, 0);
      sc[cb] = acc;
    }

    const uint32_t mw = mwords[qh * 16 + li][kt * 4 + ws];
    float p[2][4];
    float tmax = -3.0e38f;
#pragma unroll
    for (int cb = 0; cb < 2; ++cb)
#pragma unroll
      for (int r = 0; r < 4; ++r) {
        const float s =
            ((mw >> (cb * 16 + g * 4 + r)) & 1u) ? sc[cb][r] * SCALE : -1.0e9f;
        p[cb][r] = s;
        tmax = fmaxf(tmax, s);
      }
    tmax = fmaxf(tmax, __shfl_xor(tmax, 16));
    tmax = fmaxf(tmax, __shfl_xor(tmax, 32));
    const float m_new = fmaxf(m_c, tmax);
    const float alpha = __expf(m_c - m_new);
    m_c = m_new;
    float lsum = 0.f;
#pragma unroll
    for (int cb = 0; cb < 2; ++cb)
#pragma unroll
      for (int r = 0; r < 4; ++r) {
        p[cb][r] = __expf(p[cb][r] - m_new);
        lsum += p[cb][r];
      }
    l_c = l_c * alpha + lsum;

    half8 pB;
#pragma unroll
    for (int j = 0; j < 4; ++j) {
      pB[j] = (_Float16)p[0][j];
      pB[4 + j] = (_Float16)p[1][j];
    }

#pragma unroll
    for (int dblk = 0; dblk < 4; ++dblk) {
      const int d = dblk * 16 + li;
      const int rowb = d * 256;
      const int c1 = ws * 4 + (g >> 1);
      const int c2 = c1 + 2;
      const int sub = (g & 1) * 8;
      uint2 a1 = *(const uint2*)(Vlds + rowb + ((c1 ^ (li & 7)) * 16) + sub);
      uint2 a2 = *(const uint2*)(Vlds + rowb + ((c2 ^ (li & 7)) * 16) + sub);
      half8 av;
      *(uint2*)&av = a1;
      *((uint2*)&av + 1) = a2;
      O[dblk] = O[dblk] * alpha;
      O[dblk] = __builtin_amdgcn_mfma_f32_16x16x32_f16(av, pB, O[dblk], 0, 0, 0);
    }
  }

  l_c += __shfl_xor(l_c, 16);
  l_c += __shfl_xor(l_c, 32);
  if (g == 0) {
    mlbuf[w][li][0] = m_c;
    mlbuf[w][li][1] = l_c;
  }
  __syncthreads();
  float mstar = -3.0e38f;
#pragma unroll
  for (int p2 = 0; p2 < 4; ++p2)
    mstar = fmaxf(mstar, mlbuf[p2 * 2 + qh][li][0]);
  float lstar = 0.f;
#pragma unroll
  for (int p2 = 0; p2 < 4; ++p2)
    lstar += mlbuf[p2 * 2 + qh][li][1] * __expf(mlbuf[p2 * 2 + qh][li][0] - mstar);
  const float fown = __expf(m_c - mstar);
  if (g == 0 && ws == 0) {
    lstat[qh * 16 + li][0] = mstar;
    lstat[qh * 16 + li][1] = 1.f / lstar;
  }
#pragma unroll
  for (int dblk = 0; dblk < 4; ++dblk) O[dblk] = O[dblk] * fown;

  for (int ph = 0; ph < 4; ++ph) {
    if (ws == ph) {
      const int qq = qh * 16 + li;
#pragma unroll
      for (int dblk = 0; dblk < 4; ++dblk)
#pragma unroll
        for (int r = 0; r < 4; ++r) {
          const int d = dblk * 16 + g * 4 + r;
          if (ph == 0)
            Obuf[qq][d] = O[dblk][r];
          else
            Obuf[qq][d] += O[dblk][r];
        }
    }
    __syncthreads();
  }

  {
    const int qq = t >> 4;
    const int d0 = (t & 15) * 4;
    const float rl = lstat[qq][1];
    float4 o;
    o.x = Obuf[qq][d0 + 0] * rl;
    o.y = Obuf[qq][d0 + 1] * rl;
    o.z = Obuf[qq][d0 + 2] * rl;
    o.w = Obuf[qq][d0 + 3] * rl;
    *(float4*)(outsc + ((size_t)(b * SS + q0 + qq)) * DKK + d0) = o;
  }
  if (t < 32) {
    mstats[((size_t)(b * SS + q0 + t)) * 2 + 0] = lstat[t][0];
    mstats[((size_t)(b * SS + q0 + t)) * 2 + 1] = lstat[t][1];
  }
}

// ---------------------------------------------------------------------------
// Weights kernel (unchanged): streaming GEMM + exp, no LDS, no barriers.
// ---------------------------------------------------------------------------
__global__ __launch_bounds__(512) void weights_kernel(
    const _Float16* __restrict__ Qh, const _Float16* __restrict__ Kh,
    const uint32_t* __restrict__ mbits_g, const float* __restrict__ mstats,
    float* __restrict__ wts) {
  const int t = threadIdx.x;
  const int b = (int)blockIdx.x & 7;
  const int q0 = ((int)blockIdx.x >> 3) * 32;
  const int l = t & 63;
  const int li = l & 15, g = l >> 4;
  const int w = t >> 6;
  const int qh = w & 1, cq = w >> 1;
  const float SCALE = 0.125f;

  half8 aq[2];
  {
    const _Float16* qp = Qh + ((size_t)b * SS + q0 + qh * 16 + li) * DKK;
    aq[0] = *(const half8*)(qp + g * 8);
    aq[1] = *(const half8*)(qp + 32 + g * 8);
  }
  float mr[4], rl[4];
#pragma unroll
  for (int r = 0; r < 4; ++r) {
    const size_t q = (size_t)b * SS + q0 + qh * 16 + g * 4 + r;
    mr[r] = mstats[q * 2 + 0];
    rl[r] = mstats[q * 2 + 1];
  }
  const _Float16* kbase = Kh + (size_t)b * SS * DKK;

  for (int kt = 0; kt < 16; ++kt) {
    uint32_t mw[4];
#pragma unroll
    for (int r = 0; r < 4; ++r)
      mw[r] = mbits_g[((size_t)(b * SS + q0 + qh * 16 + g * 4 + r)) * 64 +
                      kt * 4 + cq];
    half8 kb[2][2];
#pragma unroll
    for (int cb = 0; cb < 2; ++cb) {
      const int krow = cq * 32 + cb * 16 + li;
      const _Float16* kp = kbase + (size_t)(kt * 128 + krow) * DKK;
      kb[cb][0] = *(const half8*)(kp + g * 8);
      kb[cb][1] = *(const half8*)(kp + 32 + g * 8);
    }
#pragma unroll
    for (int cb = 0; cb < 2; ++cb) {
      floatx4 acc = {0.f, 0.f, 0.f, 0.f};
      acc = __builtin_amdgcn_mfma_f32_16x16x32_f16(aq[0], kb[cb][0], acc, 0, 0, 0);
      acc = __builtin_amdgcn_mfma_f32_16x16x32_f16(aq[1], kb[cb][1], acc, 0, 0, 0);
#pragma unroll
      for (int r = 0; r < 4; ++r) {
        const float wv = ((mw[r] >> (cb * 16 + li)) & 1u)
                             ? __expf(acc[r] * SCALE - mr[r]) * rl[r]
                             : 0.f;
        wts[((size_t)(b * SS + q0 + qh * 16 + g * 4 + r)) * SS + kt * 128 +
            cq * 32 + cb * 16 + li] = wv;
      }
    }
  }
}

extern "C" void kernel_launch(void* const* d_in, const int* in_sizes, int n_in,
                              void* d_out, int out_size, void* d_ws, size_t ws_size,
                              hipStream_t stream) {
  (void)in_sizes; (void)n_in; (void)out_size; (void)ws_size;
  const float* k_in = (const float*)d_in[0];
  const float* q_in = (const float*)d_in[1];
  const float* v_in = (const float*)d_in[2];
  const int* mask = (const int*)d_in[3];
  const float* w_q = (const float*)d_in[4];
  const float* b_q = (const float*)d_in[5];
  const float* w_k = (const float*)d_in[6];
  const float* b_k = (const float*)d_in[7];
  const float* w_v = (const float*)d_in[8];
  const float* b_v = (const float*)d_in[9];

  float* out_scores = (float*)d_out;                        // [B,S,DK] f32
  float* out_weights = out_scores + (size_t)BB * SS * DKK;  // [B,S,S]  f32

  char* wsp = (char*)d_ws;
  const size_t nBSD = (size_t)BB * SS * DKK;
  _Float16* Qh = (_Float16*)wsp;                      // 2 MB
  _Float16* Kh = (_Float16*)(wsp + nBSD * 2);         // 2 MB
  _Float16* VhT = (_Float16*)(wsp + nBSD * 4);        // 2 MB
  uint32_t* mbits_g = (uint32_t*)(wsp + nBSD * 6);    // 4 MB
  float* mstats = (float*)(wsp + nBSD * 6 + (size_t)BB * SS * 64 * 4);  // 128 KB
  _Float16* Whi = (_Float16*)(wsp + nBSD * 6 + (size_t)BB * SS * 64 * 4 +
                              (size_t)BB * SS * 2 * 4);
  _Float16* Wlo = Whi + 3 * 65536;

  wsplit_kernel<<<96, 256, 0, stream>>>(w_q, w_k, w_v, Whi, Wlo);
  proj_kernel<<<dim3(256, 3), 512, 0, stream>>>(q_in, k_in, v_in, Whi, Wlo,
                                                b_q, b_k, b_v, Qh, Kh, VhT);
  flash_kernel<<<512, 512, 0, stream>>>(Qh, Kh, VhT, mask, out_scores,
                                        mbits_g, mstats);
  weights_kernel<<<512, 512, 0, stream>>>(Qh, Kh, mbits_g, mstats, out_weights);
}

// Round 9
// 200.383 us; speedup vs baseline: 1.2485x; 1.0379x over previous
//
#include <hip/hip_runtime.h>
#include <math.h>
#include <stdint.h>

#define BB 8
#define SS 2048
#define EE 1024
#define DKK 64

typedef _Float16 half8 __attribute__((ext_vector_type(8)));
typedef float floatx4 __attribute__((ext_vector_type(4)));

__device__ __forceinline__ void split8(float4 a, float4 b, half8& hi, half8& lo) {
  float va[8] = {a.x, a.y, a.z, a.w, b.x, b.y, b.z, b.w};
#pragma unroll
  for (int j = 0; j < 8; ++j) {
    _Float16 h = (_Float16)va[j];
    hi[j] = h;
    lo[j] = (_Float16)(va[j] - (float)h);
  }
}

// ---------------------------------------------------------------------------
// W pre-split + fragment-permute (unchanged):
//   Whi/Wlo[variant][kchunk][c][lane][8] -> B-frag load = base + lane*16B.
// ---------------------------------------------------------------------------
__global__ __launch_bounds__(256) void wsplit_kernel(
    const float* __restrict__ w_q, const float* __restrict__ w_k,
    const float* __restrict__ w_v, _Float16* __restrict__ Whi,
    _Float16* __restrict__ Wlo) {
  const int s = (int)blockIdx.x * 256 + (int)threadIdx.x;  // 0..24575
  const int l = s & 63;
  const int c = (s >> 6) & 3;
  const int ch = (s >> 8) & 31;
  const int v = s >> 13;
  const int li = l & 15, g = l >> 4;
  const float* W = v == 0 ? w_q : (v == 1 ? w_k : w_v);
  const float* src = W + (size_t)(c * 16 + li) * EE + ch * 32 + g * 8;
  float4 a = *(const float4*)src;
  float4 b = *(const float4*)(src + 4);
  half8 hi, lo;
  split8(a, b, hi, lo);
  *(half8*)(Whi + (size_t)s * 8) = hi;
  *(half8*)(Wlo + (size_t)s * 8) = lo;
}

// ---------------------------------------------------------------------------
// MFMA projection, split-fp16 (3-term), K-split across waves.
// ISSUE ORDER FIX: per phase, W fragment loads are issued FIRST and the X
// prefetch LAST, so the MFMA's vmcnt wait (for W) leaves the X loads in
// flight -- X latency now spans two full phases (true 2-deep pipeline).
// 512 thr / 8 waves; wave (rg = w&3, ks = w>>2): rows blockIdx.x*64+rg*16..+15,
// K-half ks*512..+511. Combine: ks=1 -> LDS, barrier, ks=0 adds + epilogue.
// ---------------------------------------------------------------------------
__global__ __launch_bounds__(512) void proj_kernel(
    const float* __restrict__ q_in, const float* __restrict__ k_in,
    const float* __restrict__ v_in,
    const _Float16* __restrict__ Whi, const _Float16* __restrict__ Wlo,
    const float* __restrict__ b_q, const float* __restrict__ b_k,
    const float* __restrict__ b_v,
    _Float16* __restrict__ Qh, _Float16* __restrict__ Kh,
    _Float16* __restrict__ VhT) {
  const int which = blockIdx.y;
  const float* X = which == 0 ? q_in : (which == 1 ? k_in : v_in);
  const float* bias = which == 0 ? b_q : (which == 1 ? b_k : b_v);
  const _Float16* wh = Whi + which * 65536;
  const _Float16* wl = Wlo + which * 65536;

  __shared__ float partial[4][64][16];  // [rg][lane][c*4+r] = 16 KB

  const int t = threadIdx.x;
  const int l = t & 63;
  const int li = l & 15, g = l >> 4;
  const int w = t >> 6;
  const int rg = w & 3, ks = w >> 2;
  const int row0 = (int)blockIdx.x * 64;
  const float* xrow = X + (size_t)(row0 + rg * 16 + li) * EE + ks * 512 + g * 8;
  const int ch0 = ks * 16;  // first kchunk of this half

  floatx4 acc[4];
#pragma unroll
  for (int c = 0; c < 4; ++c) acc[c] = (floatx4){0.f, 0.f, 0.f, 0.f};

  // 2-slot X pipeline (static indexing via A/B stages)
  float4 xa0 = ((const float4*)(xrow + 0 * 32))[0];
  float4 xb0 = ((const float4*)(xrow + 0 * 32))[1];
  float4 xa1 = ((const float4*)(xrow + 1 * 32))[0];
  float4 xb1 = ((const float4*)(xrow + 1 * 32))[1];

#pragma unroll 2
  for (int e = 0; e < 16; e += 2) {
    // ---- stage A: chunk e (slot 0) ----
    {
      // 1) W fragment loads FIRST (these are what the MFMAs wait on)
      half8 bh[4], bl[4];
      const int base = (ch0 + e) * 4;
#pragma unroll
      for (int c = 0; c < 4; ++c) {
        const int fo = ((base + c) * 64 + l) * 8;
        bh[c] = *(const half8*)(wh + fo);
        bl[c] = *(const half8*)(wl + fo);
      }
      // 2) X prefetch LAST (stays outstanding across the W wait)
      float4 na, nb;
      if (e + 2 < 16) {
        na = ((const float4*)(xrow + (e + 2) * 32))[0];
        nb = ((const float4*)(xrow + (e + 2) * 32))[1];
      }
      // 3) consume X loaded two phases ago
      half8 axh, axl;
      split8(xa0, xb0, axh, axl);
#pragma unroll
      for (int c = 0; c < 4; ++c) {
        acc[c] = __builtin_amdgcn_mfma_f32_16x16x32_f16(axh, bh[c], acc[c], 0, 0, 0);
        acc[c] = __builtin_amdgcn_mfma_f32_16x16x32_f16(axh, bl[c], acc[c], 0, 0, 0);
        acc[c] = __builtin_amdgcn_mfma_f32_16x16x32_f16(axl, bh[c], acc[c], 0, 0, 0);
      }
      xa0 = na;
      xb0 = nb;
    }
    // ---- stage B: chunk e+1 (slot 1) ----
    {
      half8 bh[4], bl[4];
      const int base = (ch0 + e + 1) * 4;
#pragma unroll
      for (int c = 0; c < 4; ++c) {
        const int fo = ((base + c) * 64 + l) * 8;
        bh[c] = *(const half8*)(wh + fo);
        bl[c] = *(const half8*)(wl + fo);
      }
      float4 na, nb;
      if (e + 3 < 16) {
        na = ((const float4*)(xrow + (e + 3) * 32))[0];
        nb = ((const float4*)(xrow + (e + 3) * 32))[1];
      }
      half8 axh, axl;
      split8(xa1, xb1, axh, axl);
#pragma unroll
      for (int c = 0; c < 4; ++c) {
        acc[c] = __builtin_amdgcn_mfma_f32_16x16x32_f16(axh, bh[c], acc[c], 0, 0, 0);
        acc[c] = __builtin_amdgcn_mfma_f32_16x16x32_f16(axh, bl[c], acc[c], 0, 0, 0);
        acc[c] = __builtin_amdgcn_mfma_f32_16x16x32_f16(axl, bh[c], acc[c], 0, 0, 0);
      }
      xa1 = na;
      xb1 = nb;
    }
  }

  // ---- combine the two K-halves ----
  if (ks == 1) {
#pragma unroll
    for (int c = 0; c < 4; ++c)
#pragma unroll
      for (int r = 0; r < 4; ++r) partial[rg][l][c * 4 + r] = acc[c][r];
  }
  __syncthreads();
  if (ks == 0) {
#pragma unroll
    for (int c = 0; c < 4; ++c)
#pragma unroll
      for (int r = 0; r < 4; ++r) acc[c][r] += partial[rg][l][c * 4 + r];

    float bvv[4];
#pragma unroll
    for (int c = 0; c < 4; ++c) bvv[c] = bias[c * 16 + li];

    if (which < 2) {
      _Float16* P = (which == 0) ? Qh : Kh;
#pragma unroll
      for (int c = 0; c < 4; ++c)
#pragma unroll
        for (int r = 0; r < 4; ++r)
          P[(size_t)(row0 + rg * 16 + g * 4 + r) * DKK + c * 16 + li] =
              (_Float16)(acc[c][r] + bvv[c]);
    } else {
      const int bb = row0 >> 11;
      const int s0 = row0 & (SS - 1);
#pragma unroll
      for (int c = 0; c < 4; ++c)
#pragma unroll
        for (int r = 0; r < 4; ++r)
          VhT[((size_t)bb * DKK + c * 16 + li) * SS + s0 + rg * 16 + g * 4 + r] =
              (_Float16)(acc[c][r] + bvv[c]);
    }
  }
}

// ---------------------------------------------------------------------------
// Flash kernel (unchanged): single-pass swapped-QK attention.
// ---------------------------------------------------------------------------
__global__ __launch_bounds__(512, 4) void flash_kernel(
    const _Float16* __restrict__ Qh, const _Float16* __restrict__ Kh,
    const _Float16* __restrict__ VhT, const int* __restrict__ mask,
    float* __restrict__ outsc, uint32_t* __restrict__ mbits_g,
    float* __restrict__ mstats) {
  __shared__ __align__(16) char Vlds[16384];  // [64 d][128 k] f16, swz src
  __shared__ uint32_t mwords[32][66];         // mask bits, padded
  __shared__ float Obuf[32][68];              // combine buffer, padded
  __shared__ float mlbuf[8][16][2];           // per-wave (m, l)
  __shared__ float lstat[32][2];              // per-q (m*, 1/l*)

  const int t = threadIdx.x;
  const int b = (int)blockIdx.x & 7;
  const int q0 = ((int)blockIdx.x >> 3) * 32;
  const int l = t & 63;
  const int li = l & 15, g = l >> 4;
  const int w = t >> 6;
  const int qh = w & 1, ws = w >> 1;
  const float SCALE = 0.125f;

  // ---- pack mask: thread t packs words [t*4, t*4+4) (32 ints each) ----
  {
    const int* mp = mask + ((size_t)b * SS + q0) * SS;
    uint32_t wbuf[4];
#pragma unroll
    for (int u = 0; u < 4; ++u) {
      const int word = t * 4 + u;
      const int4* src = (const int4*)(mp + word * 32);
      uint32_t bits = 0;
#pragma unroll
      for (int c = 0; c < 8; ++c) {
        int4 m4 = src[c];
        bits |= (uint32_t)(m4.x != 0) << (c * 4 + 0);
        bits |= (uint32_t)(m4.y != 0) << (c * 4 + 1);
        bits |= (uint32_t)(m4.z != 0) << (c * 4 + 2);
        bits |= (uint32_t)(m4.w != 0) << (c * 4 + 3);
      }
      wbuf[u] = bits;
      mwords[word >> 6][word & 63] = bits;
    }
    *(uint4*)(mbits_g + ((size_t)(b * SS + q0)) * 64 + t * 4) =
        *(const uint4*)wbuf;
  }

  half8 aq[2];
  {
    const _Float16* qp = Qh + ((size_t)b * SS + q0 + qh * 16 + li) * DKK;
    aq[0] = *(const half8*)(qp + g * 8);
    aq[1] = *(const half8*)(qp + 32 + g * 8);
  }

  float m_c = -3.0e38f, l_c = 0.f;
  floatx4 O[4];
#pragma unroll
  for (int d = 0; d < 4; ++d) O[d] = (floatx4){0.f, 0.f, 0.f, 0.f};

  half8 vv[2];
#pragma unroll
  for (int p = 0; p < 2; ++p) {
    const int slot = t + p * 512;
    const int vd = slot >> 4, vc = slot & 15;
    vv[p] = *(const half8*)(VhT + ((size_t)b * DKK + vd) * SS +
                            ((vc ^ (vd & 7)) * 8));
  }

  const _Float16* kbase = Kh + (size_t)b * SS * DKK;

  for (int kt = 0; kt < 16; ++kt) {
    __syncthreads();
#pragma unroll
    for (int p = 0; p < 2; ++p)
      *(half8*)(Vlds + (t + p * 512) * 16) = vv[p];
    __syncthreads();
    if (kt + 1 < 16) {
#pragma unroll
      for (int p = 0; p < 2; ++p) {
        const int slot = t + p * 512;
        const int vd = slot >> 4, vc = slot & 15;
        vv[p] = *(const half8*)(VhT + ((size_t)b * DKK + vd) * SS +
                                (kt + 1) * 128 + ((vc ^ (vd & 7)) * 8));
      }
    }

    half8 ka[2][2];
#pragma unroll
    for (int cb = 0; cb < 2; ++cb) {
      const int krow = ws * 32 + cb * 16 + li;
      const _Float16* kp = kbase + (size_t)(kt * 128 + krow) * DKK;
      ka[cb][0] = *(const half8*)(kp + g * 8);
      ka[cb][1] = *(const half8*)(kp + 32 + g * 8);
    }
    floatx4 sc[2];
#pragma unroll
    for (int cb = 0; cb < 2; ++cb) {
      floatx4 acc = {0.f, 0.f, 0.f, 0.f};
      acc = __builtin_amdgcn_mfma_f32_16x16x32_f16(ka[cb][0], aq[0], acc, 0, 0, 0);
      acc = __builtin_amdgcn_mfma_f32_16x16x32_f16(ka[cb][1], aq[1], acc, 0, 0, 0);
      sc[cb] = acc;
    }

    const uint32_t mw = mwords[qh * 16 + li][kt * 4 + ws];
    float p[2][4];
    float tmax = -3.0e38f;
#pragma unroll
    for (int cb = 0; cb < 2; ++cb)
#pragma unroll
      for (int r = 0; r < 4; ++r) {
        const float s =
            ((mw >> (cb * 16 + g * 4 + r)) & 1u) ? sc[cb][r] * SCALE : -1.0e9f;
        p[cb][r] = s;
        tmax = fmaxf(tmax, s);
      }
    tmax = fmaxf(tmax, __shfl_xor(tmax, 16));
    tmax = fmaxf(tmax, __shfl_xor(tmax, 32));
    const float m_new = fmaxf(m_c, tmax);
    const float alpha = __expf(m_c - m_new);
    m_c = m_new;
    float lsum = 0.f;
#pragma unroll
    for (int cb = 0; cb < 2; ++cb)
#pragma unroll
      for (int r = 0; r < 4; ++r) {
        p[cb][r] = __expf(p[cb][r] - m_new);
        lsum += p[cb][r];
      }
    l_c = l_c * alpha + lsum;

    half8 pB;
#pragma unroll
    for (int j = 0; j < 4; ++j) {
      pB[j] = (_Float16)p[0][j];
      pB[4 + j] = (_Float16)p[1][j];
    }

#pragma unroll
    for (int dblk = 0; dblk < 4; ++dblk) {
      const int d = dblk * 16 + li;
      const int rowb = d * 256;
      const int c1 = ws * 4 + (g >> 1);
      const int c2 = c1 + 2;
      const int sub = (g & 1) * 8;
      uint2 a1 = *(const uint2*)(Vlds + rowb + ((c1 ^ (li & 7)) * 16) + sub);
      uint2 a2 = *(const uint2*)(Vlds + rowb + ((c2 ^ (li & 7)) * 16) + sub);
      half8 av;
      *(uint2*)&av = a1;
      *((uint2*)&av + 1) = a2;
      O[dblk] = O[dblk] * alpha;
      O[dblk] = __builtin_amdgcn_mfma_f32_16x16x32_f16(av, pB, O[dblk], 0, 0, 0);
    }
  }

  l_c += __shfl_xor(l_c, 16);
  l_c += __shfl_xor(l_c, 32);
  if (g == 0) {
    mlbuf[w][li][0] = m_c;
    mlbuf[w][li][1] = l_c;
  }
  __syncthreads();
  float mstar = -3.0e38f;
#pragma unroll
  for (int p2 = 0; p2 < 4; ++p2)
    mstar = fmaxf(mstar, mlbuf[p2 * 2 + qh][li][0]);
  float lstar = 0.f;
#pragma unroll
  for (int p2 = 0; p2 < 4; ++p2)
    lstar += mlbuf[p2 * 2 + qh][li][1] * __expf(mlbuf[p2 * 2 + qh][li][0] - mstar);
  const float fown = __expf(m_c - mstar);
  if (g == 0 && ws == 0) {
    lstat[qh * 16 + li][0] = mstar;
    lstat[qh * 16 + li][1] = 1.f / lstar;
  }
#pragma unroll
  for (int dblk = 0; dblk < 4; ++dblk) O[dblk] = O[dblk] * fown;

  for (int ph = 0; ph < 4; ++ph) {
    if (ws == ph) {
      const int qq = qh * 16 + li;
#pragma unroll
      for (int dblk = 0; dblk < 4; ++dblk)
#pragma unroll
        for (int r = 0; r < 4; ++r) {
          const int d = dblk * 16 + g * 4 + r;
          if (ph == 0)
            Obuf[qq][d] = O[dblk][r];
          else
            Obuf[qq][d] += O[dblk][r];
        }
    }
    __syncthreads();
  }

  {
    const int qq = t >> 4;
    const int d0 = (t & 15) * 4;
    const float rl = lstat[qq][1];
    float4 o;
    o.x = Obuf[qq][d0 + 0] * rl;
    o.y = Obuf[qq][d0 + 1] * rl;
    o.z = Obuf[qq][d0 + 2] * rl;
    o.w = Obuf[qq][d0 + 3] * rl;
    *(float4*)(outsc + ((size_t)(b * SS + q0 + qq)) * DKK + d0) = o;
  }
  if (t < 32) {
    mstats[((size_t)(b * SS + q0 + t)) * 2 + 0] = lstat[t][0];
    mstats[((size_t)(b * SS + q0 + t)) * 2 + 1] = lstat[t][1];
  }
}

// ---------------------------------------------------------------------------
// Weights kernel (unchanged): streaming GEMM + exp, no LDS, no barriers.
// ---------------------------------------------------------------------------
__global__ __launch_bounds__(512) void weights_kernel(
    const _Float16* __restrict__ Qh, const _Float16* __restrict__ Kh,
    const uint32_t* __restrict__ mbits_g, const float* __restrict__ mstats,
    float* __restrict__ wts) {
  const int t = threadIdx.x;
  const int b = (int)blockIdx.x & 7;
  const int q0 = ((int)blockIdx.x >> 3) * 32;
  const int l = t & 63;
  const int li = l & 15, g = l >> 4;
  const int w = t >> 6;
  const int qh = w & 1, cq = w >> 1;
  const float SCALE = 0.125f;

  half8 aq[2];
  {
    const _Float16* qp = Qh + ((size_t)b * SS + q0 + qh * 16 + li) * DKK;
    aq[0] = *(const half8*)(qp + g * 8);
    aq[1] = *(const half8*)(qp + 32 + g * 8);
  }
  float mr[4], rl[4];
#pragma unroll
  for (int r = 0; r < 4; ++r) {
    const size_t q = (size_t)b * SS + q0 + qh * 16 + g * 4 + r;
    mr[r] = mstats[q * 2 + 0];
    rl[r] = mstats[q * 2 + 1];
  }
  const _Float16* kbase = Kh + (size_t)b * SS * DKK;

  for (int kt = 0; kt < 16; ++kt) {
    uint32_t mw[4];
#pragma unroll
    for (int r = 0; r < 4; ++r)
      mw[r] = mbits_g[((size_t)(b * SS + q0 + qh * 16 + g * 4 + r)) * 64 +
                      kt * 4 + cq];
    half8 kb[2][2];
#pragma unroll
    for (int cb = 0; cb < 2; ++cb) {
      const int krow = cq * 32 + cb * 16 + li;
      const _Float16* kp = kbase + (size_t)(kt * 128 + krow) * DKK;
      kb[cb][0] = *(const half8*)(kp + g * 8);
      kb[cb][1] = *(const half8*)(kp + 32 + g * 8);
    }
#pragma unroll
    for (int cb = 0; cb < 2; ++cb) {
      floatx4 acc = {0.f, 0.f, 0.f, 0.f};
      acc = __builtin_amdgcn_mfma_f32_16x16x32_f16(aq[0], kb[cb][0], acc, 0, 0, 0);
      acc = __builtin_amdgcn_mfma_f32_16x16x32_f16(aq[1], kb[cb][1], acc, 0, 0, 0);
#pragma unroll
      for (int r = 0; r < 4; ++r) {
        const float wv = ((mw[r] >> (cb * 16 + li)) & 1u)
                             ? __expf(acc[r] * SCALE - mr[r]) * rl[r]
                             : 0.f;
        wts[((size_t)(b * SS + q0 + qh * 16 + g * 4 + r)) * SS + kt * 128 +
            cq * 32 + cb * 16 + li] = wv;
      }
    }
  }
}

extern "C" void kernel_launch(void* const* d_in, const int* in_sizes, int n_in,
                              void* d_out, int out_size, void* d_ws, size_t ws_size,
                              hipStream_t stream) {
  (void)in_sizes; (void)n_in; (void)out_size; (void)ws_size;
  const float* k_in = (const float*)d_in[0];
  const float* q_in = (const float*)d_in[1];
  const float* v_in = (const float*)d_in[2];
  const int* mask = (const int*)d_in[3];
  const float* w_q = (const float*)d_in[4];
  const float* b_q = (const float*)d_in[5];
  const float* w_k = (const float*)d_in[6];
  const float* b_k = (const float*)d_in[7];
  const float* w_v = (const float*)d_in[8];
  const float* b_v = (const float*)d_in[9];

  float* out_scores = (float*)d_out;                        // [B,S,DK] f32
  float* out_weights = out_scores + (size_t)BB * SS * DKK;  // [B,S,S]  f32

  char* wsp = (char*)d_ws;
  const size_t nBSD = (size_t)BB * SS * DKK;
  _Float16* Qh = (_Float16*)wsp;                      // 2 MB
  _Float16* Kh = (_Float16*)(wsp + nBSD * 2);         // 2 MB
  _Float16* VhT = (_Float16*)(wsp + nBSD * 4);        // 2 MB
  uint32_t* mbits_g = (uint32_t*)(wsp + nBSD * 6);    // 4 MB
  float* mstats = (float*)(wsp + nBSD * 6 + (size_t)BB * SS * 64 * 4);  // 128 KB
  _Float16* Whi = (_Float16*)(wsp + nBSD * 6 + (size_t)BB * SS * 64 * 4 +
                              (size_t)BB * SS * 2 * 4);
  _Float16* Wlo = Whi + 3 * 65536;

  wsplit_kernel<<<96, 256, 0, stream>>>(w_q, w_k, w_v, Whi, Wlo);
  proj_kernel<<<dim3(256, 3), 512, 0, stream>>>(q_in, k_in, v_in, Whi, Wlo,
                                                b_q, b_k, b_v, Qh, Kh, VhT);
  flash_kernel<<<512, 512, 0, stream>>>(Qh, Kh, VhT, mask, out_scores,
                                        mbits_g, mstats);
  weights_kernel<<<512, 512, 0, stream>>>(Qh, Kh, mbits_g, mstats, out_weights);
}

// Round 10
// 192.374 us; speedup vs baseline: 1.3005x; 1.0416x over previous
//
#include <hip/hip_runtime.h>
#include <math.h>
#include <stdint.h>

#define BB 8
#define SS 2048
#define EE 1024
#define DKK 64

typedef _Float16 half8 __attribute__((ext_vector_type(8)));
typedef float floatx4 __attribute__((ext_vector_type(4)));

__device__ __forceinline__ void split8(float4 a, float4 b, half8& hi, half8& lo) {
  float va[8] = {a.x, a.y, a.z, a.w, b.x, b.y, b.z, b.w};
#pragma unroll
  for (int j = 0; j < 8; ++j) {
    _Float16 h = (_Float16)va[j];
    hi[j] = h;
    lo[j] = (_Float16)(va[j] - (float)h);
  }
}

__device__ __forceinline__ half8 cvt8(float4 a, float4 b) {
  half8 h;
  h[0] = (_Float16)a.x; h[1] = (_Float16)a.y; h[2] = (_Float16)a.z; h[3] = (_Float16)a.w;
  h[4] = (_Float16)b.x; h[5] = (_Float16)b.y; h[6] = (_Float16)b.z; h[7] = (_Float16)b.w;
  return h;
}

#define GLOAD_LDS16(gsrc, ldst)                                      \
  __builtin_amdgcn_global_load_lds(                                  \
      (const __attribute__((address_space(1))) void*)(gsrc),         \
      (__attribute__((address_space(3))) void*)(ldst), 16, 0, 0)

// ---------------------------------------------------------------------------
// W pre-split + fragment-permute (unchanged):
//   Whi/Wlo[variant][kchunk][c][lane][8] -> B-frag load = base + lane*16B.
// ---------------------------------------------------------------------------
__global__ __launch_bounds__(256) void wsplit_kernel(
    const float* __restrict__ w_q, const float* __restrict__ w_k,
    const float* __restrict__ w_v, _Float16* __restrict__ Whi,
    _Float16* __restrict__ Wlo) {
  const int s = (int)blockIdx.x * 256 + (int)threadIdx.x;  // 0..24575
  const int l = s & 63;
  const int c = (s >> 6) & 3;
  const int ch = (s >> 8) & 31;
  const int v = s >> 13;
  const int li = l & 15, g = l >> 4;
  const float* W = v == 0 ? w_q : (v == 1 ? w_k : w_v);
  const float* src = W + (size_t)(c * 16 + li) * EE + ch * 32 + g * 8;
  float4 a = *(const float4*)src;
  float4 b = *(const float4*)(src + 4);
  half8 hi, lo;
  split8(a, b, hi, lo);
  *(half8*)(Whi + (size_t)s * 8) = hi;
  *(half8*)(Wlo + (size_t)s * 8) = lo;
}

// ---------------------------------------------------------------------------
// MFMA projection, split-fp16 (3-term): P = Xh*Wh + Xh*Wl + Xl*Wh + bias.
// m97 pattern: X staged via global_load_lds (16B), TRIPLE-buffered LDS,
// ONE barrier per iter, stage issued at iter top (2 chunks ahead) so the
// next barrier's vmcnt drain lands after a full compute phase.
// X LDS layout linear; source pre-swizzled (chunk ^ (row&7)) so fragment
// ds_read_b128 are ~2-way max. W: fragment-permuted coalesced (L2-hot).
// 256 thr / 4 waves; wave rg: rows blockIdx.x*64 + rg*16 .. +15, 64 cols.
// V output: LDS transpose -> coalesced half8 stores.
// ---------------------------------------------------------------------------
__global__ __launch_bounds__(256) void proj_kernel(
    const float* __restrict__ q_in, const float* __restrict__ k_in,
    const float* __restrict__ v_in,
    const _Float16* __restrict__ Whi, const _Float16* __restrict__ Wlo,
    const float* __restrict__ b_q, const float* __restrict__ b_k,
    const float* __restrict__ b_v,
    _Float16* __restrict__ Qh, _Float16* __restrict__ Kh,
    _Float16* __restrict__ VhT) {
  const int which = blockIdx.y;
  const float* X = which == 0 ? q_in : (which == 1 ? k_in : v_in);
  const float* bias = which == 0 ? b_q : (which == 1 ? b_k : b_v);
  const _Float16* wh = Whi + which * 65536;
  const _Float16* wl = Wlo + which * 65536;

  __shared__ __align__(16) float Xs[3][4096];  // 3 x 16KB (64 rows x 64 f32)

  const int t = threadIdx.x;
  const int l = t & 63;
  const int li = l & 15, g = l >> 4;
  const int rg = t >> 6;
  const int row0 = (int)blockIdx.x * 64;
  const int r = rg * 16 + li;   // this lane's A-row
  const int rs = r & 7;         // read swizzle

  // staging slot for this thread: 4 slots of 16B per iter
  const int srow0 = t >> 4, spc = t & 15;

  floatx4 acc[4];
#pragma unroll
  for (int c = 0; c < 4; ++c) acc[c] = (floatx4){0.f, 0.f, 0.f, 0.f};

#define STAGE(buf, e)                                                       \
  {                                                                         \
    _Pragma("unroll") for (int u = 0; u < 4; ++u) {                         \
      const int row = srow0 + u * 16;                                       \
      const float* src = X + (size_t)(row0 + row) * EE + (e) * 64 +         \
                         ((spc ^ (row & 7)) << 2);                          \
      GLOAD_LDS16(src, &Xs[buf][(row * 16 + spc) * 4]);                     \
    }                                                                       \
  }

  STAGE(0, 0);
  STAGE(1, 1);

  for (int e = 0; e < 16; ++e) {
    const int cur = e - (e / 3) * 3;  // e % 3
    __syncthreads();  // staged data for buf `cur` visible; prev readers done
    if (e + 2 < 16) {
      const int nxt = (e + 2) - ((e + 2) / 3) * 3;
      STAGE(nxt, e + 2);  // in flight across this whole compute phase
    }
    // A-fragments from LDS
    half8 axh[2], axl[2];
#pragma unroll
    for (int h = 0; h < 2; ++h) {
      const int pc0 = h * 8 + g * 2;
      float4 xa = *(const float4*)&Xs[cur][r * 64 + ((pc0 ^ rs) << 2)];
      float4 xb = *(const float4*)&Xs[cur][r * 64 + (((pc0 + 1) ^ rs) << 2)];
      split8(xa, xb, axh[h], axl[h]);
    }
    // B-fragments (coalesced, L2-hot) + MFMAs
#pragma unroll
    for (int c = 0; c < 4; ++c) {
#pragma unroll
      for (int h = 0; h < 2; ++h) {
        const int fo = (((e * 2 + h) * 4 + c) * 64 + l) * 8;
        const half8 bh = *(const half8*)(wh + fo);
        const half8 bl = *(const half8*)(wl + fo);
        acc[c] = __builtin_amdgcn_mfma_f32_16x16x32_f16(axh[h], bh, acc[c], 0, 0, 0);
        acc[c] = __builtin_amdgcn_mfma_f32_16x16x32_f16(axh[h], bl, acc[c], 0, 0, 0);
        acc[c] = __builtin_amdgcn_mfma_f32_16x16x32_f16(axl[h], bh, acc[c], 0, 0, 0);
      }
    }
  }
#undef STAGE

  float bvv[4];
#pragma unroll
  for (int c = 0; c < 4; ++c) bvv[c] = bias[c * 16 + li];

  if (which < 2) {
    _Float16* P = (which == 0) ? Qh : Kh;
#pragma unroll
    for (int c = 0; c < 4; ++c)
#pragma unroll
      for (int rr = 0; rr < 4; ++rr)
        P[(size_t)(row0 + rg * 16 + g * 4 + rr) * DKK + c * 16 + li] =
            (_Float16)(acc[c][rr] + bvv[c]);
  } else {
    // transpose in LDS (reuse Xs), then coalesced half8 stores
    __syncthreads();  // all waves done with Xs
    float* Tt = &Xs[0][0];  // [64 d][65]
#pragma unroll
    for (int c = 0; c < 4; ++c)
#pragma unroll
      for (int rr = 0; rr < 4; ++rr)
        Tt[(c * 16 + li) * 65 + rg * 16 + g * 4 + rr] = acc[c][rr] + bvv[c];
    __syncthreads();
    const int bb = row0 >> 11;
    const int s0 = row0 & (SS - 1);
    const int d = t >> 2, sc0 = (t & 3) * 16;
    const float* trow = &Tt[d * 65 + sc0];
    float4 v0 = {trow[0], trow[1], trow[2], trow[3]};
    float4 v1 = {trow[4], trow[5], trow[6], trow[7]};
    float4 v2 = {trow[8], trow[9], trow[10], trow[11]};
    float4 v3 = {trow[12], trow[13], trow[14], trow[15]};
    _Float16* dst = VhT + ((size_t)bb * DKK + d) * SS + s0 + sc0;
    *(half8*)dst = cvt8(v0, v1);
    *(half8*)(dst + 8) = cvt8(v2, v3);
  }
}

// ---------------------------------------------------------------------------
// Flash kernel (unchanged): single-pass swapped-QK attention.
// ---------------------------------------------------------------------------
__global__ __launch_bounds__(512, 4) void flash_kernel(
    const _Float16* __restrict__ Qh, const _Float16* __restrict__ Kh,
    const _Float16* __restrict__ VhT, const int* __restrict__ mask,
    float* __restrict__ outsc, uint32_t* __restrict__ mbits_g,
    float* __restrict__ mstats) {
  __shared__ __align__(16) char Vlds[16384];  // [64 d][128 k] f16, swz src
  __shared__ uint32_t mwords[32][66];         // mask bits, padded
  __shared__ float Obuf[32][68];              // combine buffer, padded
  __shared__ float mlbuf[8][16][2];           // per-wave (m, l)
  __shared__ float lstat[32][2];              // per-q (m*, 1/l*)

  const int t = threadIdx.x;
  const int b = (int)blockIdx.x & 7;
  const int q0 = ((int)blockIdx.x >> 3) * 32;
  const int l = t & 63;
  const int li = l & 15, g = l >> 4;
  const int w = t >> 6;
  const int qh = w & 1, ws = w >> 1;
  const float SCALE = 0.125f;

  // ---- pack mask: thread t packs words [t*4, t*4+4) (32 ints each) ----
  {
    const int* mp = mask + ((size_t)b * SS + q0) * SS;
    uint32_t wbuf[4];
#pragma unroll
    for (int u = 0; u < 4; ++u) {
      const int word = t * 4 + u;
      const int4* src = (const int4*)(mp + word * 32);
      uint32_t bits = 0;
#pragma unroll
      for (int c = 0; c < 8; ++c) {
        int4 m4 = src[c];
        bits |= (uint32_t)(m4.x != 0) << (c * 4 + 0);
        bits |= (uint32_t)(m4.y != 0) << (c * 4 + 1);
        bits |= (uint32_t)(m4.z != 0) << (c * 4 + 2);
        bits |= (uint32_t)(m4.w != 0) << (c * 4 + 3);
      }
      wbuf[u] = bits;
      mwords[word >> 6][word & 63] = bits;
    }
    *(uint4*)(mbits_g + ((size_t)(b * SS + q0)) * 64 + t * 4) =
        *(const uint4*)wbuf;
  }

  half8 aq[2];
  {
    const _Float16* qp = Qh + ((size_t)b * SS + q0 + qh * 16 + li) * DKK;
    aq[0] = *(const half8*)(qp + g * 8);
    aq[1] = *(const half8*)(qp + 32 + g * 8);
  }

  float m_c = -3.0e38f, l_c = 0.f;
  floatx4 O[4];
#pragma unroll
  for (int d = 0; d < 4; ++d) O[d] = (floatx4){0.f, 0.f, 0.f, 0.f};

  half8 vv[2];
#pragma unroll
  for (int p = 0; p < 2; ++p) {
    const int slot = t + p * 512;
    const int vd = slot >> 4, vc = slot & 15;
    vv[p] = *(const half8*)(VhT + ((size_t)b * DKK + vd) * SS +
                            ((vc ^ (vd & 7)) * 8));
  }

  const _Float16* kbase = Kh + (size_t)b * SS * DKK;

  for (int kt = 0; kt < 16; ++kt) {
    __syncthreads();
#pragma unroll
    for (int p = 0; p < 2; ++p)
      *(half8*)(Vlds + (t + p * 512) * 16) = vv[p];
    __syncthreads();
    if (kt + 1 < 16) {
#pragma unroll
      for (int p = 0; p < 2; ++p) {
        const int slot = t + p * 512;
        const int vd = slot >> 4, vc = slot & 15;
        vv[p] = *(const half8*)(VhT + ((size_t)b * DKK + vd) * SS +
                                (kt + 1) * 128 + ((vc ^ (vd & 7)) * 8));
      }
    }

    half8 ka[2][2];
#pragma unroll
    for (int cb = 0; cb < 2; ++cb) {
      const int krow = ws * 32 + cb * 16 + li;
      const _Float16* kp = kbase + (size_t)(kt * 128 + krow) * DKK;
      ka[cb][0] = *(const half8*)(kp + g * 8);
      ka[cb][1] = *(const half8*)(kp + 32 + g * 8);
    }
    floatx4 sc[2];
#pragma unroll
    for (int cb = 0; cb < 2; ++cb) {
      floatx4 acc = {0.f, 0.f, 0.f, 0.f};
      acc = __builtin_amdgcn_mfma_f32_16x16x32_f16(ka[cb][0], aq[0], acc, 0, 0, 0);
      acc = __builtin_amdgcn_mfma_f32_16x16x32_f16(ka[cb][1], aq[1], acc, 0, 0, 0);
      sc[cb] = acc;
    }

    const uint32_t mw = mwords[qh * 16 + li][kt * 4 + ws];
    float p[2][4];
    float tmax = -3.0e38f;
#pragma unroll
    for (int cb = 0; cb < 2; ++cb)
#pragma unroll
      for (int r = 0; r < 4; ++r) {
        const float s =
            ((mw >> (cb * 16 + g * 4 + r)) & 1u) ? sc[cb][r] * SCALE : -1.0e9f;
        p[cb][r] = s;
        tmax = fmaxf(tmax, s);
      }
    tmax = fmaxf(tmax, __shfl_xor(tmax, 16));
    tmax = fmaxf(tmax, __shfl_xor(tmax, 32));
    const float m_new = fmaxf(m_c, tmax);
    const float alpha = __expf(m_c - m_new);
    m_c = m_new;
    float lsum = 0.f;
#pragma unroll
    for (int cb = 0; cb < 2; ++cb)
#pragma unroll
      for (int r = 0; r < 4; ++r) {
        p[cb][r] = __expf(p[cb][r] - m_new);
        lsum += p[cb][r];
      }
    l_c = l_c * alpha + lsum;

    half8 pB;
#pragma unroll
    for (int j = 0; j < 4; ++j) {
      pB[j] = (_Float16)p[0][j];
      pB[4 + j] = (_Float16)p[1][j];
    }

#pragma unroll
    for (int dblk = 0; dblk < 4; ++dblk) {
      const int d = dblk * 16 + li;
      const int rowb = d * 256;
      const int c1 = ws * 4 + (g >> 1);
      const int c2 = c1 + 2;
      const int sub = (g & 1) * 8;
      uint2 a1 = *(const uint2*)(Vlds + rowb + ((c1 ^ (li & 7)) * 16) + sub);
      uint2 a2 = *(const uint2*)(Vlds + rowb + ((c2 ^ (li & 7)) * 16) + sub);
      half8 av;
      *(uint2*)&av = a1;
      *((uint2*)&av + 1) = a2;
      O[dblk] = O[dblk] * alpha;
      O[dblk] = __builtin_amdgcn_mfma_f32_16x16x32_f16(av, pB, O[dblk], 0, 0, 0);
    }
  }

  l_c += __shfl_xor(l_c, 16);
  l_c += __shfl_xor(l_c, 32);
  if (g == 0) {
    mlbuf[w][li][0] = m_c;
    mlbuf[w][li][1] = l_c;
  }
  __syncthreads();
  float mstar = -3.0e38f;
#pragma unroll
  for (int p2 = 0; p2 < 4; ++p2)
    mstar = fmaxf(mstar, mlbuf[p2 * 2 + qh][li][0]);
  float lstar = 0.f;
#pragma unroll
  for (int p2 = 0; p2 < 4; ++p2)
    lstar += mlbuf[p2 * 2 + qh][li][1] * __expf(mlbuf[p2 * 2 + qh][li][0] - mstar);
  const float fown = __expf(m_c - mstar);
  if (g == 0 && ws == 0) {
    lstat[qh * 16 + li][0] = mstar;
    lstat[qh * 16 + li][1] = 1.f / lstar;
  }
#pragma unroll
  for (int dblk = 0; dblk < 4; ++dblk) O[dblk] = O[dblk] * fown;

  for (int ph = 0; ph < 4; ++ph) {
    if (ws == ph) {
      const int qq = qh * 16 + li;
#pragma unroll
      for (int dblk = 0; dblk < 4; ++dblk)
#pragma unroll
        for (int r = 0; r < 4; ++r) {
          const int d = dblk * 16 + g * 4 + r;
          if (ph == 0)
            Obuf[qq][d] = O[dblk][r];
          else
            Obuf[qq][d] += O[dblk][r];
        }
    }
    __syncthreads();
  }

  {
    const int qq = t >> 4;
    const int d0 = (t & 15) * 4;
    const float rl = lstat[qq][1];
    float4 o;
    o.x = Obuf[qq][d0 + 0] * rl;
    o.y = Obuf[qq][d0 + 1] * rl;
    o.z = Obuf[qq][d0 + 2] * rl;
    o.w = Obuf[qq][d0 + 3] * rl;
    *(float4*)(outsc + ((size_t)(b * SS + q0 + qq)) * DKK + d0) = o;
  }
  if (t < 32) {
    mstats[((size_t)(b * SS + q0 + t)) * 2 + 0] = lstat[t][0];
    mstats[((size_t)(b * SS + q0 + t)) * 2 + 1] = lstat[t][1];
  }
}

// ---------------------------------------------------------------------------
// Weights kernel (unchanged): streaming GEMM + exp, no LDS, no barriers.
// ---------------------------------------------------------------------------
__global__ __launch_bounds__(512) void weights_kernel(
    const _Float16* __restrict__ Qh, const _Float16* __restrict__ Kh,
    const uint32_t* __restrict__ mbits_g, const float* __restrict__ mstats,
    float* __restrict__ wts) {
  const int t = threadIdx.x;
  const int b = (int)blockIdx.x & 7;
  const int q0 = ((int)blockIdx.x >> 3) * 32;
  const int l = t & 63;
  const int li = l & 15, g = l >> 4;
  const int w = t >> 6;
  const int qh = w & 1, cq = w >> 1;
  const float SCALE = 0.125f;

  half8 aq[2];
  {
    const _Float16* qp = Qh + ((size_t)b * SS + q0 + qh * 16 + li) * DKK;
    aq[0] = *(const half8*)(qp + g * 8);
    aq[1] = *(const half8*)(qp + 32 + g * 8);
  }
  float mr[4], rl[4];
#pragma unroll
  for (int r = 0; r < 4; ++r) {
    const size_t q = (size_t)b * SS + q0 + qh * 16 + g * 4 + r;
    mr[r] = mstats[q * 2 + 0];
    rl[r] = mstats[q * 2 + 1];
  }
  const _Float16* kbase = Kh + (size_t)b * SS * DKK;

  for (int kt = 0; kt < 16; ++kt) {
    uint32_t mw[4];
#pragma unroll
    for (int r = 0; r < 4; ++r)
      mw[r] = mbits_g[((size_t)(b * SS + q0 + qh * 16 + g * 4 + r)) * 64 +
                      kt * 4 + cq];
    half8 kb[2][2];
#pragma unroll
    for (int cb = 0; cb < 2; ++cb) {
      const int krow = cq * 32 + cb * 16 + li;
      const _Float16* kp = kbase + (size_t)(kt * 128 + krow) * DKK;
      kb[cb][0] = *(const half8*)(kp + g * 8);
      kb[cb][1] = *(const half8*)(kp + 32 + g * 8);
    }
#pragma unroll
    for (int cb = 0; cb < 2; ++cb) {
      floatx4 acc = {0.f, 0.f, 0.f, 0.f};
      acc = __builtin_amdgcn_mfma_f32_16x16x32_f16(aq[0], kb[cb][0], acc, 0, 0, 0);
      acc = __builtin_amdgcn_mfma_f32_16x16x32_f16(aq[1], kb[cb][1], acc, 0, 0, 0);
#pragma unroll
      for (int r = 0; r < 4; ++r) {
        const float wv = ((mw[r] >> (cb * 16 + li)) & 1u)
                             ? __expf(acc[r] * SCALE - mr[r]) * rl[r]
                             : 0.f;
        wts[((size_t)(b * SS + q0 + qh * 16 + g * 4 + r)) * SS + kt * 128 +
            cq * 32 + cb * 16 + li] = wv;
      }
    }
  }
}

extern "C" void kernel_launch(void* const* d_in, const int* in_sizes, int n_in,
                              void* d_out, int out_size, void* d_ws, size_t ws_size,
                              hipStream_t stream) {
  (void)in_sizes; (void)n_in; (void)out_size; (void)ws_size;
  const float* k_in = (const float*)d_in[0];
  const float* q_in = (const float*)d_in[1];
  const float* v_in = (const float*)d_in[2];
  const int* mask = (const int*)d_in[3];
  const float* w_q = (const float*)d_in[4];
  const float* b_q = (const float*)d_in[5];
  const float* w_k = (const float*)d_in[6];
  const float* b_k = (const float*)d_in[7];
  const float* w_v = (const float*)d_in[8];
  const float* b_v = (const float*)d_in[9];

  float* out_scores = (float*)d_out;                        // [B,S,DK] f32
  float* out_weights = out_scores + (size_t)BB * SS * DKK;  // [B,S,S]  f32

  char* wsp = (char*)d_ws;
  const size_t nBSD = (size_t)BB * SS * DKK;
  _Float16* Qh = (_Float16*)wsp;                      // 2 MB
  _Float16* Kh = (_Float16*)(wsp + nBSD * 2);         // 2 MB
  _Float16* VhT = (_Float16*)(wsp + nBSD * 4);        // 2 MB
  uint32_t* mbits_g = (uint32_t*)(wsp + nBSD * 6);    // 4 MB
  float* mstats = (float*)(wsp + nBSD * 6 + (size_t)BB * SS * 64 * 4);  // 128 KB
  _Float16* Whi = (_Float16*)(wsp + nBSD * 6 + (size_t)BB * SS * 64 * 4 +
                              (size_t)BB * SS * 2 * 4);
  _Float16* Wlo = Whi + 3 * 65536;

  wsplit_kernel<<<96, 256, 0, stream>>>(w_q, w_k, w_v, Whi, Wlo);
  proj_kernel<<<dim3(256, 3), 256, 0, stream>>>(q_in, k_in, v_in, Whi, Wlo,
                                                b_q, b_k, b_v, Qh, Kh, VhT);
  flash_kernel<<<512, 512, 0, stream>>>(Qh, Kh, VhT, mask, out_scores,
                                        mbits_g, mstats);
  weights_kernel<<<512, 512, 0, stream>>>(Qh, Kh, mbits_g, mstats, out_weights);
}

// Round 11
// 179.996 us; speedup vs baseline: 1.3900x; 1.0688x over previous
//
#include <hip/hip_runtime.h>
#include <math.h>
#include <stdint.h>

#define BB 8
#define SS 2048
#define EE 1024
#define DKK 64

typedef _Float16 half8 __attribute__((ext_vector_type(8)));
typedef float floatx4 __attribute__((ext_vector_type(4)));

__device__ __forceinline__ half8 cvt8(float4 a, float4 b) {
  half8 h;
  h[0] = (_Float16)a.x; h[1] = (_Float16)a.y; h[2] = (_Float16)a.z; h[3] = (_Float16)a.w;
  h[4] = (_Float16)b.x; h[5] = (_Float16)b.y; h[6] = (_Float16)b.z; h[7] = (_Float16)b.w;
  return h;
}

__device__ __forceinline__ void split8(float4 a, float4 b, half8& hi, half8& lo) {
  float va[8] = {a.x, a.y, a.z, a.w, b.x, b.y, b.z, b.w};
#pragma unroll
  for (int j = 0; j < 8; ++j) {
    _Float16 h = (_Float16)va[j];
    hi[j] = h;
    lo[j] = (_Float16)(va[j] - (float)h);
  }
}

// ---------------------------------------------------------------------------
// MFMA projection via split-fp16 (3-term), fp16 outputs.  RESTORED from R4
// (measured ~50 us there; barrier-free rewrites R5-R10 were all slower).
// blockIdx.y = 0:Q, 1:K, 2:V(transposed out). Tile 64x64, BK=64, 4 waves.
// X and W staged in LDS as fp16 hi/lo (register-prefetched fp32, split,
// XOR-swizzled 16B chunks); inner loop reads fragments from LDS only.
// ---------------------------------------------------------------------------
__global__ __launch_bounds__(256, 3) void proj_kernel(
    const float* __restrict__ q_in, const float* __restrict__ k_in,
    const float* __restrict__ v_in,
    const float* __restrict__ w_q, const float* __restrict__ b_q,
    const float* __restrict__ w_k, const float* __restrict__ b_k,
    const float* __restrict__ w_v, const float* __restrict__ b_v,
    _Float16* __restrict__ Qh, _Float16* __restrict__ Kh,
    _Float16* __restrict__ VhT) {
  const int which = blockIdx.y;
  const float* X = which == 0 ? q_in : (which == 1 ? k_in : v_in);
  const float* W = which == 0 ? w_q : (which == 1 ? w_k : w_v);
  const float* bias = which == 0 ? b_q : (which == 1 ? b_k : b_v);

  __shared__ __align__(16) char Xh[64 * 128];
  __shared__ __align__(16) char Xl[64 * 128];
  __shared__ __align__(16) char Wh[64 * 128];
  __shared__ __align__(16) char Wl[64 * 128];

  const int t = threadIdx.x;
  const int row0 = blockIdx.x * 64;
  const int sr = t >> 2;
  const int c4 = t & 3;
  const int l = t & 63;
  const int li = l & 15, g = l >> 4;
  const int w = t >> 6;

  const float* xbase = X + (size_t)(row0 + sr) * EE + c4 * 16;
  const float* wbase = W + (size_t)sr * EE + c4 * 16;

  float4 xr[4], wr[4];
#pragma unroll
  for (int u = 0; u < 4; ++u) {
    xr[u] = ((const float4*)xbase)[u];
    wr[u] = ((const float4*)wbase)[u];
  }

  floatx4 acc[4];
#pragma unroll
  for (int c = 0; c < 4; ++c) acc[c] = (floatx4){0.f, 0.f, 0.f, 0.f};

  const int xrow_off = (w * 16 + li) * 128;
  const int swz = li & 7;

  for (int e0 = 0; e0 < EE; e0 += 64) {
    half8 xh0, xl0, xh1, xl1, wh0, wl0, wh1, wl1;
    split8(xr[0], xr[1], xh0, xl0);
    split8(xr[2], xr[3], xh1, xl1);
    split8(wr[0], wr[1], wh0, wl0);
    split8(wr[2], wr[3], wh1, wl1);
    __syncthreads();
    {
      const int p0 = ((c4 * 2 + 0) ^ (sr & 7)) * 16;
      const int p1 = ((c4 * 2 + 1) ^ (sr & 7)) * 16;
      *(half8*)(Xh + sr * 128 + p0) = xh0;
      *(half8*)(Xh + sr * 128 + p1) = xh1;
      *(half8*)(Xl + sr * 128 + p0) = xl0;
      *(half8*)(Xl + sr * 128 + p1) = xl1;
      *(half8*)(Wh + sr * 128 + p0) = wh0;
      *(half8*)(Wh + sr * 128 + p1) = wh1;
      *(half8*)(Wl + sr * 128 + p0) = wl0;
      *(half8*)(Wl + sr * 128 + p1) = wl1;
    }
    if (e0 + 64 < EE) {
#pragma unroll
      for (int u = 0; u < 4; ++u) {
        xr[u] = ((const float4*)(xbase + e0 + 64))[u];
        wr[u] = ((const float4*)(wbase + e0 + 64))[u];
      }
    }
    __syncthreads();
    half8 axh[2], axl[2];
#pragma unroll
    for (int h = 0; h < 2; ++h) {
      const int apos = ((h * 4 + g) ^ swz) * 16;
      axh[h] = *(const half8*)(Xh + xrow_off + apos);
      axl[h] = *(const half8*)(Xl + xrow_off + apos);
    }
#pragma unroll
    for (int c = 0; c < 4; ++c) {
      const int brow_off = (c * 16 + li) * 128;
#pragma unroll
      for (int h = 0; h < 2; ++h) {
        const int bpos = ((h * 4 + g) ^ swz) * 16;
        half8 bh = *(const half8*)(Wh + brow_off + bpos);
        half8 bl = *(const half8*)(Wl + brow_off + bpos);
        acc[c] = __builtin_amdgcn_mfma_f32_16x16x32_f16(axh[h], bh, acc[c], 0, 0, 0);
        acc[c] = __builtin_amdgcn_mfma_f32_16x16x32_f16(axh[h], bl, acc[c], 0, 0, 0);
        acc[c] = __builtin_amdgcn_mfma_f32_16x16x32_f16(axl[h], bh, acc[c], 0, 0, 0);
      }
    }
  }

  float bvv[4];
#pragma unroll
  for (int c = 0; c < 4; ++c) bvv[c] = bias[c * 16 + li];

  if (which < 2) {
    _Float16* P = (which == 0) ? Qh : Kh;
#pragma unroll
    for (int c = 0; c < 4; ++c)
#pragma unroll
      for (int r = 0; r < 4; ++r)
        P[(size_t)(row0 + w * 16 + g * 4 + r) * DKK + c * 16 + li] =
            (_Float16)(acc[c][r] + bvv[c]);
  } else {
    const int bb = row0 >> 11;
    const int s0 = row0 & (SS - 1);
#pragma unroll
    for (int c = 0; c < 4; ++c)
#pragma unroll
      for (int r = 0; r < 4; ++r)
        VhT[((size_t)bb * DKK + c * 16 + li) * SS + s0 + w * 16 + g * 4 + r] =
            (_Float16)(acc[c][r] + bvv[c]);
  }
}

// ---------------------------------------------------------------------------
// Flash kernel (unchanged): single-pass swapped-QK attention.
// ---------------------------------------------------------------------------
__global__ __launch_bounds__(512, 4) void flash_kernel(
    const _Float16* __restrict__ Qh, const _Float16* __restrict__ Kh,
    const _Float16* __restrict__ VhT, const int* __restrict__ mask,
    float* __restrict__ outsc, uint32_t* __restrict__ mbits_g,
    float* __restrict__ mstats) {
  __shared__ __align__(16) char Vlds[16384];  // [64 d][128 k] f16, swz src
  __shared__ uint32_t mwords[32][66];         // mask bits, padded
  __shared__ float Obuf[32][68];              // combine buffer, padded
  __shared__ float mlbuf[8][16][2];           // per-wave (m, l)
  __shared__ float lstat[32][2];              // per-q (m*, 1/l*)

  const int t = threadIdx.x;
  const int b = (int)blockIdx.x & 7;
  const int q0 = ((int)blockIdx.x >> 3) * 32;
  const int l = t & 63;
  const int li = l & 15, g = l >> 4;
  const int w = t >> 6;
  const int qh = w & 1, ws = w >> 1;
  const float SCALE = 0.125f;

  // ---- pack mask: thread t packs words [t*4, t*4+4) (32 ints each) ----
  {
    const int* mp = mask + ((size_t)b * SS + q0) * SS;
    uint32_t wbuf[4];
#pragma unroll
    for (int u = 0; u < 4; ++u) {
      const int word = t * 4 + u;
      const int4* src = (const int4*)(mp + word * 32);
      uint32_t bits = 0;
#pragma unroll
      for (int c = 0; c < 8; ++c) {
        int4 m4 = src[c];
        bits |= (uint32_t)(m4.x != 0) << (c * 4 + 0);
        bits |= (uint32_t)(m4.y != 0) << (c * 4 + 1);
        bits |= (uint32_t)(m4.z != 0) << (c * 4 + 2);
        bits |= (uint32_t)(m4.w != 0) << (c * 4 + 3);
      }
      wbuf[u] = bits;
      mwords[word >> 6][word & 63] = bits;
    }
    *(uint4*)(mbits_g + ((size_t)(b * SS + q0)) * 64 + t * 4) =
        *(const uint4*)wbuf;
  }

  half8 aq[2];
  {
    const _Float16* qp = Qh + ((size_t)b * SS + q0 + qh * 16 + li) * DKK;
    aq[0] = *(const half8*)(qp + g * 8);
    aq[1] = *(const half8*)(qp + 32 + g * 8);
  }

  float m_c = -3.0e38f, l_c = 0.f;
  floatx4 O[4];
#pragma unroll
  for (int d = 0; d < 4; ++d) O[d] = (floatx4){0.f, 0.f, 0.f, 0.f};

  half8 vv[2];
#pragma unroll
  for (int p = 0; p < 2; ++p) {
    const int slot = t + p * 512;
    const int vd = slot >> 4, vc = slot & 15;
    vv[p] = *(const half8*)(VhT + ((size_t)b * DKK + vd) * SS +
                            ((vc ^ (vd & 7)) * 8));
  }

  const _Float16* kbase = Kh + (size_t)b * SS * DKK;

  for (int kt = 0; kt < 16; ++kt) {
    __syncthreads();
#pragma unroll
    for (int p = 0; p < 2; ++p)
      *(half8*)(Vlds + (t + p * 512) * 16) = vv[p];
    __syncthreads();
    if (kt + 1 < 16) {
#pragma unroll
      for (int p = 0; p < 2; ++p) {
        const int slot = t + p * 512;
        const int vd = slot >> 4, vc = slot & 15;
        vv[p] = *(const half8*)(VhT + ((size_t)b * DKK + vd) * SS +
                                (kt + 1) * 128 + ((vc ^ (vd & 7)) * 8));
      }
    }

    half8 ka[2][2];
#pragma unroll
    for (int cb = 0; cb < 2; ++cb) {
      const int krow = ws * 32 + cb * 16 + li;
      const _Float16* kp = kbase + (size_t)(kt * 128 + krow) * DKK;
      ka[cb][0] = *(const half8*)(kp + g * 8);
      ka[cb][1] = *(const half8*)(kp + 32 + g * 8);
    }
    floatx4 sc[2];
#pragma unroll
    for (int cb = 0; cb < 2; ++cb) {
      floatx4 acc = {0.f, 0.f, 0.f, 0.f};
      acc = __builtin_amdgcn_mfma_f32_16x16x32_f16(ka[cb][0], aq[0], acc, 0, 0, 0);
      acc = __builtin_amdgcn_mfma_f32_16x16x32_f16(ka[cb][1], aq[1], acc, 0, 0, 0);
      sc[cb] = acc;
    }

    const uint32_t mw = mwords[qh * 16 + li][kt * 4 + ws];
    float p[2][4];
    float tmax = -3.0e38f;
#pragma unroll
    for (int cb = 0; cb < 2; ++cb)
#pragma unroll
      for (int r = 0; r < 4; ++r) {
        const float s =
            ((mw >> (cb * 16 + g * 4 + r)) & 1u) ? sc[cb][r] * SCALE : -1.0e9f;
        p[cb][r] = s;
        tmax = fmaxf(tmax, s);
      }
    tmax = fmaxf(tmax, __shfl_xor(tmax, 16));
    tmax = fmaxf(tmax, __shfl_xor(tmax, 32));
    const float m_new = fmaxf(m_c, tmax);
    const float alpha = __expf(m_c - m_new);
    m_c = m_new;
    float lsum = 0.f;
#pragma unroll
    for (int cb = 0; cb < 2; ++cb)
#pragma unroll
      for (int r = 0; r < 4; ++r) {
        p[cb][r] = __expf(p[cb][r] - m_new);
        lsum += p[cb][r];
      }
    l_c = l_c * alpha + lsum;

    half8 pB;
#pragma unroll
    for (int j = 0; j < 4; ++j) {
      pB[j] = (_Float16)p[0][j];
      pB[4 + j] = (_Float16)p[1][j];
    }

#pragma unroll
    for (int dblk = 0; dblk < 4; ++dblk) {
      const int d = dblk * 16 + li;
      const int rowb = d * 256;
      const int c1 = ws * 4 + (g >> 1);
      const int c2 = c1 + 2;
      const int sub = (g & 1) * 8;
      uint2 a1 = *(const uint2*)(Vlds + rowb + ((c1 ^ (li & 7)) * 16) + sub);
      uint2 a2 = *(const uint2*)(Vlds + rowb + ((c2 ^ (li & 7)) * 16) + sub);
      half8 av;
      *(uint2*)&av = a1;
      *((uint2*)&av + 1) = a2;
      O[dblk] = O[dblk] * alpha;
      O[dblk] = __builtin_amdgcn_mfma_f32_16x16x32_f16(av, pB, O[dblk], 0, 0, 0);
    }
  }

  l_c += __shfl_xor(l_c, 16);
  l_c += __shfl_xor(l_c, 32);
  if (g == 0) {
    mlbuf[w][li][0] = m_c;
    mlbuf[w][li][1] = l_c;
  }
  __syncthreads();
  float mstar = -3.0e38f;
#pragma unroll
  for (int p2 = 0; p2 < 4; ++p2)
    mstar = fmaxf(mstar, mlbuf[p2 * 2 + qh][li][0]);
  float lstar = 0.f;
#pragma unroll
  for (int p2 = 0; p2 < 4; ++p2)
    lstar += mlbuf[p2 * 2 + qh][li][1] * __expf(mlbuf[p2 * 2 + qh][li][0] - mstar);
  const float fown = __expf(m_c - mstar);
  if (g == 0 && ws == 0) {
    lstat[qh * 16 + li][0] = mstar;
    lstat[qh * 16 + li][1] = 1.f / lstar;
  }
#pragma unroll
  for (int dblk = 0; dblk < 4; ++dblk) O[dblk] = O[dblk] * fown;

  for (int ph = 0; ph < 4; ++ph) {
    if (ws == ph) {
      const int qq = qh * 16 + li;
#pragma unroll
      for (int dblk = 0; dblk < 4; ++dblk)
#pragma unroll
        for (int r = 0; r < 4; ++r) {
          const int d = dblk * 16 + g * 4 + r;
          if (ph == 0)
            Obuf[qq][d] = O[dblk][r];
          else
            Obuf[qq][d] += O[dblk][r];
        }
    }
    __syncthreads();
  }

  {
    const int qq = t >> 4;
    const int d0 = (t & 15) * 4;
    const float rl = lstat[qq][1];
    float4 o;
    o.x = Obuf[qq][d0 + 0] * rl;
    o.y = Obuf[qq][d0 + 1] * rl;
    o.z = Obuf[qq][d0 + 2] * rl;
    o.w = Obuf[qq][d0 + 3] * rl;
    *(float4*)(outsc + ((size_t)(b * SS + q0 + qq)) * DKK + d0) = o;
  }
  if (t < 32) {
    mstats[((size_t)(b * SS + q0 + t)) * 2 + 0] = lstat[t][0];
    mstats[((size_t)(b * SS + q0 + t)) * 2 + 1] = lstat[t][1];
  }
}

// ---------------------------------------------------------------------------
// Weights kernel (unchanged): streaming GEMM + exp, no LDS, no barriers.
// ---------------------------------------------------------------------------
__global__ __launch_bounds__(512) void weights_kernel(
    const _Float16* __restrict__ Qh, const _Float16* __restrict__ Kh,
    const uint32_t* __restrict__ mbits_g, const float* __restrict__ mstats,
    float* __restrict__ wts) {
  const int t = threadIdx.x;
  const int b = (int)blockIdx.x & 7;
  const int q0 = ((int)blockIdx.x >> 3) * 32;
  const int l = t & 63;
  const int li = l & 15, g = l >> 4;
  const int w = t >> 6;
  const int qh = w & 1, cq = w >> 1;
  const float SCALE = 0.125f;

  half8 aq[2];
  {
    const _Float16* qp = Qh + ((size_t)b * SS + q0 + qh * 16 + li) * DKK;
    aq[0] = *(const half8*)(qp + g * 8);
    aq[1] = *(const half8*)(qp + 32 + g * 8);
  }
  float mr[4], rl[4];
#pragma unroll
  for (int r = 0; r < 4; ++r) {
    const size_t q = (size_t)b * SS + q0 + qh * 16 + g * 4 + r;
    mr[r] = mstats[q * 2 + 0];
    rl[r] = mstats[q * 2 + 1];
  }
  const _Float16* kbase = Kh + (size_t)b * SS * DKK;

  for (int kt = 0; kt < 16; ++kt) {
    uint32_t mw[4];
#pragma unroll
    for (int r = 0; r < 4; ++r)
      mw[r] = mbits_g[((size_t)(b * SS + q0 + qh * 16 + g * 4 + r)) * 64 +
                      kt * 4 + cq];
    half8 kb[2][2];
#pragma unroll
    for (int cb = 0; cb < 2; ++cb) {
      const int krow = cq * 32 + cb * 16 + li;
      const _Float16* kp = kbase + (size_t)(kt * 128 + krow) * DKK;
      kb[cb][0] = *(const half8*)(kp + g * 8);
      kb[cb][1] = *(const half8*)(kp + 32 + g * 8);
    }
#pragma unroll
    for (int cb = 0; cb < 2; ++cb) {
      floatx4 acc = {0.f, 0.f, 0.f, 0.f};
      acc = __builtin_amdgcn_mfma_f32_16x16x32_f16(aq[0], kb[cb][0], acc, 0, 0, 0);
      acc = __builtin_amdgcn_mfma_f32_16x16x32_f16(aq[1], kb[cb][1], acc, 0, 0, 0);
#pragma unroll
      for (int r = 0; r < 4; ++r) {
        const float wv = ((mw[r] >> (cb * 16 + li)) & 1u)
                             ? __expf(acc[r] * SCALE - mr[r]) * rl[r]
                             : 0.f;
        wts[((size_t)(b * SS + q0 + qh * 16 + g * 4 + r)) * SS + kt * 128 +
            cq * 32 + cb * 16 + li] = wv;
      }
    }
  }
}

extern "C" void kernel_launch(void* const* d_in, const int* in_sizes, int n_in,
                              void* d_out, int out_size, void* d_ws, size_t ws_size,
                              hipStream_t stream) {
  (void)in_sizes; (void)n_in; (void)out_size; (void)ws_size;
  const float* k_in = (const float*)d_in[0];
  const float* q_in = (const float*)d_in[1];
  const float* v_in = (const float*)d_in[2];
  const int* mask = (const int*)d_in[3];
  const float* w_q = (const float*)d_in[4];
  const float* b_q = (const float*)d_in[5];
  const float* w_k = (const float*)d_in[6];
  const float* b_k = (const float*)d_in[7];
  const float* w_v = (const float*)d_in[8];
  const float* b_v = (const float*)d_in[9];

  float* out_scores = (float*)d_out;                        // [B,S,DK] f32
  float* out_weights = out_scores + (size_t)BB * SS * DKK;  // [B,S,S]  f32

  char* wsp = (char*)d_ws;
  const size_t nBSD = (size_t)BB * SS * DKK;
  _Float16* Qh = (_Float16*)wsp;                      // 2 MB
  _Float16* Kh = (_Float16*)(wsp + nBSD * 2);         // 2 MB
  _Float16* VhT = (_Float16*)(wsp + nBSD * 4);        // 2 MB
  uint32_t* mbits_g = (uint32_t*)(wsp + nBSD * 6);    // 4 MB
  float* mstats = (float*)(wsp + nBSD * 6 + (size_t)BB * SS * 64 * 4);  // 128 KB

  proj_kernel<<<dim3(256, 3), 256, 0, stream>>>(q_in, k_in, v_in, w_q, b_q,
                                                w_k, b_k, w_v, b_v, Qh, Kh, VhT);
  flash_kernel<<<512, 512, 0, stream>>>(Qh, Kh, VhT, mask, out_scores,
                                        mbits_g, mstats);
  weights_kernel<<<512, 512, 0, stream>>>(Qh, Kh, mbits_g, mstats, out_weights);
}